// Round 1
// baseline (826.119 us; speedup 1.0000x reference)
//
#include <hip/hip_runtime.h>
#include <math.h>

#define NN 20000
#define EE 320000
#define ET 340000   // EE + NN self loops
#define NG 16
#define DD 256
#define NH 4

__device__ __forceinline__ float gelu_f(float x){
  float x3 = x*x*x;
  return 0.5f*x*(1.0f + tanhf(0.7978845608028654f*(x + 0.044715f*x3)));
}
__device__ __forceinline__ float lrelu_f(float x){ return x > 0.f ? x : 0.2f*x; }

// ---------------- CSR build ----------------
__global__ void hist_k(const int* __restrict__ ei, int* __restrict__ deg){
  int i = blockIdx.x*256 + threadIdx.x;
  if (i >= ET) return;
  int dst = (i < EE) ? ei[EE + i] : (i - EE);
  atomicAdd(&deg[dst], 1);
}

__global__ void scan_k(int* __restrict__ deg){
  __shared__ int buf[1024];
  __shared__ int carry;
  int t = threadIdx.x;
  if (t == 0) carry = 0;
  __syncthreads();
  for (int base = 0; base < NN; base += 1024){
    int i = base + t;
    int v = (i < NN) ? deg[i] : 0;
    buf[t] = v;
    __syncthreads();
    for (int ofs = 1; ofs < 1024; ofs <<= 1){
      int add = (t >= ofs) ? buf[t-ofs] : 0;
      __syncthreads();
      buf[t] += add;
      __syncthreads();
    }
    int excl = buf[t] - v + carry;
    if (i < NN) deg[i] = excl;
    __syncthreads();
    if (t == 1023) carry += buf[1023];
    __syncthreads();
  }
  if (t == 0) deg[NN] = carry;
}

__global__ void scatter_k(const int* __restrict__ ei, const int* __restrict__ off,
                          int* __restrict__ cur, int* __restrict__ cs, int* __restrict__ ce){
  int i = blockIdx.x*256 + threadIdx.x;
  if (i >= ET) return;
  int src, dst;
  if (i < EE){ src = ei[i]; dst = ei[EE + i]; } else { src = i - EE; dst = src; }
  int pos = off[dst] + atomicAdd(&cur[dst], 1);
  cs[pos] = src; ce[pos] = i;
}

// ---------------- conv1 (input dim 1 -> algebraic collapse) ----------------
__global__ void conv1_pre_k(const float* __restrict__ W1, const float* __restrict__ as1,
                            const float* __restrict__ ad1, float* __restrict__ ST){
  int t = threadIdx.x;                    // 256 threads = 4 waves, wave w == head w
  float w = W1[t];
  float p = w*as1[t], q = w*ad1[t];
  for (int ofs = 32; ofs > 0; ofs >>= 1){
    p += __shfl_down(p, ofs, 64);
    q += __shfl_down(q, ofs, 64);
  }
  if ((t & 63) == 0){ ST[t>>6] = p; ST[4 + (t>>6)] = q; }
}

__global__ void conv1_agg_k(const float* __restrict__ x, const int* __restrict__ off,
                            const int* __restrict__ cs, const float* __restrict__ ST,
                            float* __restrict__ s4){
  int d = blockIdx.x*256 + threadIdx.x;
  if (d >= NN) return;
  float S[4], T[4];
  #pragma unroll
  for (int hh = 0; hh < 4; hh++){ S[hh] = ST[hh]; T[hh] = ST[4+hh]; }
  float xd = x[d];
  int o0 = off[d], o1 = off[d+1];
  float m[4] = {-1e30f,-1e30f,-1e30f,-1e30f};
  for (int k = o0; k < o1; k++){
    float xs = x[cs[k]];
    #pragma unroll
    for (int hh = 0; hh < 4; hh++)
      m[hh] = fmaxf(m[hh], lrelu_f(xs*S[hh] + xd*T[hh]));
  }
  float den[4] = {0,0,0,0}, ac[4] = {0,0,0,0};
  for (int k = o0; k < o1; k++){
    float xs = x[cs[k]];
    #pragma unroll
    for (int hh = 0; hh < 4; hh++){
      float ex = expf(lrelu_f(xs*S[hh] + xd*T[hh]) - m[hh]);
      den[hh] += ex; ac[hh] += ex*xs;
    }
  }
  #pragma unroll
  for (int hh = 0; hh < 4; hh++) s4[d*4+hh] = ac[hh]/(den[hh] + 1e-16f);
}

__global__ void conv1_fin_k(const float* __restrict__ W1, const float* __restrict__ b1,
                            const float* __restrict__ s4, float* __restrict__ h){
  int i = blockIdx.x*256 + threadIdx.x;   // grid = NN blocks
  int n = i >> 8; int c = i & 255;
  float v = W1[c]*s4[n*4 + (c>>6)] + b1[c];
  h[i] = gelu_f(v);
}

// ---------------- f32 GEMM: C[M,256] = A[M,256] @ B[256,256] ----------------
__global__ __launch_bounds__(256) void gemm_k(const float* __restrict__ A,
                                              const float* __restrict__ B,
                                              float* __restrict__ C, int M){
  __shared__ float As[64][17];
  __shared__ float Bs[16][64];
  int tid = threadIdx.x;
  int tx = tid & 15, ty = tid >> 4;
  int bm = blockIdx.x*64, bn = blockIdx.y*64;
  float acc[4][4] = {};
  for (int k0 = 0; k0 < 256; k0 += 16){
    {
      int e = tid*4;
      int r = e >> 4, c = e & 15;
      int row = bm + r;
      float4 v = make_float4(0.f,0.f,0.f,0.f);
      if (row < M) v = *(const float4*)&A[row*256 + k0 + c];
      As[r][c+0] = v.x; As[r][c+1] = v.y; As[r][c+2] = v.z; As[r][c+3] = v.w;
    }
    {
      int e = tid*4;
      int r = e >> 6, c = e & 63;
      float4 v = *(const float4*)&B[(k0+r)*256 + bn + c];
      Bs[r][c+0] = v.x; Bs[r][c+1] = v.y; Bs[r][c+2] = v.z; Bs[r][c+3] = v.w;
    }
    __syncthreads();
    #pragma unroll
    for (int kk = 0; kk < 16; kk++){
      float a[4], b[4];
      #pragma unroll
      for (int i = 0; i < 4; i++) a[i] = As[ty*4+i][kk];
      #pragma unroll
      for (int j = 0; j < 4; j++) b[j] = Bs[kk][tx*4+j];
      #pragma unroll
      for (int i = 0; i < 4; i++)
        #pragma unroll
        for (int j = 0; j < 4; j++) acc[i][j] += a[i]*b[j];
    }
    __syncthreads();
  }
  #pragma unroll
  for (int i = 0; i < 4; i++){
    int row = bm + ty*4 + i;
    if (row < M)
      #pragma unroll
      for (int j = 0; j < 4; j++) C[row*256 + bn + tx*4 + j] = acc[i][j];
  }
}

// ---------------- per-node attention scalars ----------------
__global__ void asd_k(const float* __restrict__ g, const float* __restrict__ as,
                      const float* __restrict__ ad, float* __restrict__ a_s,
                      float* __restrict__ a_d){
  int gw = (blockIdx.x*256 + threadIdx.x) >> 6;   // wave id == node
  int lane = threadIdx.x & 63;
  if (gw >= NN) return;
  const float* row = g + gw*256;
  float p = 0.f, q = 0.f;
  #pragma unroll
  for (int j = 0; j < 4; j++){
    float v = row[lane + 64*j];
    p += v*as[lane + 64*j];
    q += v*ad[lane + 64*j];
  }
  for (int ofs = 32; ofs > 0; ofs >>= 1){
    p += __shfl_down(p, ofs, 64);
    q += __shfl_down(q, ofs, 64);
  }
  if (lane == 0){ a_s[gw] = p; a_d[gw] = q; }
}

// ---------------- conv2 aggregation (block per dst node) ----------------
__global__ __launch_bounds__(256) void agg2_k(const float* __restrict__ g,
    const float* __restrict__ a_s, const float* __restrict__ a_d,
    const int* __restrict__ off, const int* __restrict__ cs, const int* __restrict__ ce,
    const float* __restrict__ b2l, float* __restrict__ hout, float* __restrict__ alpha_out){
  int d = blockIdx.x;
  int t = threadIdx.x;
  int o0 = off[d], o1 = off[d+1];
  float add = a_d[d];
  float m = -1e30f;
  for (int k = o0; k < o1; k++) m = fmaxf(m, lrelu_f(a_s[cs[k]] + add));
  float den = 0.f, acc = 0.f;
  for (int k = o0; k < o1; k++){
    int s = cs[k];
    float ex = expf(lrelu_f(a_s[s] + add) - m);
    den += ex;
    acc += ex * g[s*256 + t];
  }
  float inv = 1.0f/(den + 1e-16f);
  hout[d*256 + t] = gelu_f(acc*inv + b2l[t]);
  if (alpha_out){
    for (int k = o0 + t; k < o1; k += 256){
      int s = cs[k];
      float ex = expf(lrelu_f(a_s[s] + add) - m);
      alpha_out[ce[k]] = ex*inv;
    }
  }
}

// ---------------- pooling + MLP head ----------------
__global__ void pool_k(const float* __restrict__ h, const int* __restrict__ batch,
                       float* __restrict__ pool){
  __shared__ float lp[NG*256];
  int t = threadIdx.x;
  for (int gg = 0; gg < NG; gg++) lp[gg*256 + t] = 0.f;
  for (int n = blockIdx.x; n < NN; n += gridDim.x){
    int b = batch[n];
    lp[b*256 + t] += h[n*256 + t];
  }
  for (int gg = 0; gg < NG; gg++) atomicAdd(&pool[gg*256 + t], lp[gg*256 + t]);
}

__global__ void cnt_k(const int* __restrict__ batch, float* __restrict__ cnts){
  int n = blockIdx.x*256 + threadIdx.x;
  if (n < NN) atomicAdd(&cnts[batch[n]], 1.0f);
}

__global__ void mlp_k(const float* __restrict__ pool, const float* __restrict__ cnts,
                      const float* __restrict__ Wl1, const float* __restrict__ bl1,
                      const float* __restrict__ Wl2, const float* __restrict__ bl2,
                      const float* __restrict__ Wl3, const float* __restrict__ bl3,
                      float* __restrict__ out){
  __shared__ float mean[256];
  __shared__ float z1[128];
  __shared__ float z2[64];
  int g = blockIdx.x, t = threadIdx.x;
  mean[t] = pool[g*256 + t] / cnts[g];
  __syncthreads();
  if (t < 128){
    float s = bl1[t];
    for (int k = 0; k < 256; k++) s += mean[k]*Wl1[k*128 + t];
    z1[t] = gelu_f(s);
  }
  __syncthreads();
  if (t < 64){
    float s = bl2[t];
    for (int k = 0; k < 128; k++) s += z1[k]*Wl2[k*64 + t];
    z2[t] = gelu_f(s);
  }
  __syncthreads();
  if (t == 0){
    float s = bl3[0];
    for (int k = 0; k < 64; k++) s += z2[k]*Wl3[k];
    out[g] = 1.f/(1.f + expf(-s));
  }
}

__global__ void eout_k(const int* __restrict__ ei, float* __restrict__ out){
  int i = blockIdx.x*256 + threadIdx.x;
  if (i >= ET) return;
  float s, d;
  if (i < EE){ s = (float)ei[i]; d = (float)ei[EE + i]; }
  else { s = (float)(i - EE); d = s; }
  out[16 + i] = s;
  out[16 + ET + i] = d;
}

extern "C" void kernel_launch(void* const* d_in, const int* in_sizes, int n_in,
                              void* d_out, int out_size, void* d_ws, size_t ws_size,
                              hipStream_t stream) {
  const float* x   = (const float*)d_in[0];
  const int*   ei  = (const int*)d_in[1];
  const int*   batch = (const int*)d_in[2];
  const float* W1  = (const float*)d_in[3];
  const float* as1 = (const float*)d_in[4];
  const float* ad1 = (const float*)d_in[5];
  const float* b1  = (const float*)d_in[6];
  const float* W2  = (const float*)d_in[7];
  const float* as2 = (const float*)d_in[8];
  const float* ad2 = (const float*)d_in[9];
  const float* b2  = (const float*)d_in[10];
  const float* Wl1 = (const float*)d_in[11];
  const float* bl1 = (const float*)d_in[12];
  const float* Wl2 = (const float*)d_in[13];
  const float* bl2 = (const float*)d_in[14];
  const float* Wl3 = (const float*)d_in[15];
  const float* bl3 = (const float*)d_in[16];
  float* out = (float*)d_out;

  float* g    = (float*)d_ws;            // N*D
  float* h    = g   + NN*DD;             // N*D
  float* a_s  = h   + NN*DD;             // N*NH (conv2 uses [0..N))
  float* a_d  = a_s + NN*NH;
  float* s4   = a_d + NN*NH;             // N*NH
  float* ST   = s4  + NN*NH;             // 8
  float* pool = ST  + 8;                 // NG*D
  float* cnts = pool + NG*DD;            // NG
  int* ideg   = (int*)(cnts + NG);       // N+1 (offsets after scan)
  int* icur   = ideg + (NN + 1);         // N
  int* csr_s  = icur + NN;               // ET
  int* csr_e  = csr_s + ET;              // ET

  hipMemsetAsync(ideg, 0, sizeof(int)*(2*NN + 1), stream);
  hipMemsetAsync(pool, 0, sizeof(float)*(NG*DD + NG), stream);

  hist_k<<<(ET + 255)/256, 256, 0, stream>>>(ei, ideg);
  scan_k<<<1, 1024, 0, stream>>>(ideg);
  scatter_k<<<(ET + 255)/256, 256, 0, stream>>>(ei, ideg, icur, csr_s, csr_e);

  conv1_pre_k<<<1, 256, 0, stream>>>(W1, as1, ad1, ST);
  conv1_agg_k<<<(NN + 255)/256, 256, 0, stream>>>(x, ideg, csr_s, ST, s4);
  conv1_fin_k<<<NN, 256, 0, stream>>>(W1, b1, s4, h);

  for (int l = 0; l < 3; l++){
    gemm_k<<<dim3((NN + 63)/64, 4), 256, 0, stream>>>(h, W2 + l*DD*DD, g, NN);
    asd_k<<<(NN*64 + 255)/256, 256, 0, stream>>>(g, as2 + l*DD, ad2 + l*DD, a_s, a_d);
    agg2_k<<<NN, 256, 0, stream>>>(g, a_s, a_d, ideg, csr_s, csr_e, b2 + l*DD, h,
                                   (l == 2) ? (out + 16 + 2*ET) : (float*)nullptr);
  }

  pool_k<<<64, 256, 0, stream>>>(h, batch, pool);
  cnt_k<<<(NN + 255)/256, 256, 0, stream>>>(batch, cnts);
  mlp_k<<<NG, 256, 0, stream>>>(pool, cnts, Wl1, bl1, Wl2, bl2, Wl3, bl3, out);
  eout_k<<<(ET + 255)/256, 256, 0, stream>>>(ei, out);
}

// Round 2
// 541.522 us; speedup vs baseline: 1.5256x; 1.5256x over previous
//
#include <hip/hip_runtime.h>
#include <hip/hip_bf16.h>
#include <math.h>

#define NN 20000
#define EE 320000
#define ET 340000   // EE + NN self loops
#define NG 16
#define DD 256
#define NH 4

typedef __attribute__((ext_vector_type(8))) short bf16x8;
typedef __attribute__((ext_vector_type(4))) float f32x4;

__device__ __forceinline__ float gelu_f(float x){
  float x3 = x*x*x;
  return 0.5f*x*(1.0f + tanhf(0.7978845608028654f*(x + 0.044715f*x3)));
}
__device__ __forceinline__ float lrelu_f(float x){ return x > 0.f ? x : 0.2f*x; }
__device__ __forceinline__ unsigned short f2b(float f){
  __hip_bfloat16 b = __float2bfloat16(f);
  return *(unsigned short*)&b;
}
__device__ __forceinline__ float b2f(unsigned short u){
  __hip_bfloat16 b; *(unsigned short*)&b = u;
  return __bfloat162float(b);
}

// ---------------- CSR build ----------------
__global__ void hist_k(const int* __restrict__ ei, int* __restrict__ deg){
  int i = blockIdx.x*256 + threadIdx.x;
  if (i >= ET) return;
  int dst = (i < EE) ? ei[EE + i] : (i - EE);
  atomicAdd(&deg[dst], 1);
}

__global__ void scan_k(int* __restrict__ deg){
  __shared__ int wsum[16];
  __shared__ int carry;
  int t = threadIdx.x, lane = t & 63, w = t >> 6;
  if (t == 0) carry = 0;
  __syncthreads();
  for (int base = 0; base < NN; base += 1024){
    int i = base + t;
    int v = (i < NN) ? deg[i] : 0;
    int s = v;
    #pragma unroll
    for (int ofs = 1; ofs < 64; ofs <<= 1){
      int u = __shfl_up(s, ofs, 64);
      if (lane >= ofs) s += u;
    }
    if (lane == 63) wsum[w] = s;
    __syncthreads();
    if (w == 0 && lane < 16){
      int ws = wsum[lane];
      #pragma unroll
      for (int ofs = 1; ofs < 16; ofs <<= 1){
        int u = __shfl_up(ws, ofs, 64);
        if (lane >= ofs) ws += u;
      }
      wsum[lane] = ws;
    }
    __syncthreads();
    int excl = s - v + (w > 0 ? wsum[w-1] : 0) + carry;
    if (i < NN) deg[i] = excl;
    __syncthreads();
    if (t == 0) carry += wsum[15];
    __syncthreads();
  }
  if (t == 0) deg[NN] = carry;
}

__global__ void scatter_k(const int* __restrict__ ei, const int* __restrict__ off,
                          int* __restrict__ cur, int* __restrict__ cs, int* __restrict__ ce){
  int i = blockIdx.x*256 + threadIdx.x;
  if (i >= ET) return;
  int src, dst;
  if (i < EE){ src = ei[i]; dst = ei[EE + i]; } else { src = i - EE; dst = src; }
  int pos = off[dst] + atomicAdd(&cur[dst], 1);
  cs[pos] = src; ce[pos] = i;
}

// ---------------- conv1 (input dim 1 -> algebraic collapse) ----------------
__global__ void conv1_pre_k(const float* __restrict__ W1, const float* __restrict__ as1,
                            const float* __restrict__ ad1, float* __restrict__ ST){
  int t = threadIdx.x;
  float w = W1[t];
  float p = w*as1[t], q = w*ad1[t];
  for (int ofs = 32; ofs > 0; ofs >>= 1){
    p += __shfl_down(p, ofs, 64);
    q += __shfl_down(q, ofs, 64);
  }
  if ((t & 63) == 0){ ST[t>>6] = p; ST[4 + (t>>6)] = q; }
}

__global__ void conv1_agg_k(const float* __restrict__ x, const int* __restrict__ off,
                            const int* __restrict__ cs, const float* __restrict__ ST,
                            float* __restrict__ s4){
  int d = blockIdx.x*256 + threadIdx.x;
  if (d >= NN) return;
  float S[4], T[4];
  #pragma unroll
  for (int hh = 0; hh < 4; hh++){ S[hh] = ST[hh]; T[hh] = ST[4+hh]; }
  float xd = x[d];
  int o0 = off[d], o1 = off[d+1];
  float m[4] = {-1e30f,-1e30f,-1e30f,-1e30f};
  for (int k = o0; k < o1; k++){
    float xs = x[cs[k]];
    #pragma unroll
    for (int hh = 0; hh < 4; hh++)
      m[hh] = fmaxf(m[hh], lrelu_f(xs*S[hh] + xd*T[hh]));
  }
  float den[4] = {0,0,0,0}, ac[4] = {0,0,0,0};
  for (int k = o0; k < o1; k++){
    float xs = x[cs[k]];
    #pragma unroll
    for (int hh = 0; hh < 4; hh++){
      float ex = expf(lrelu_f(xs*S[hh] + xd*T[hh]) - m[hh]);
      den[hh] += ex; ac[hh] += ex*xs;
    }
  }
  #pragma unroll
  for (int hh = 0; hh < 4; hh++) s4[d*4+hh] = ac[hh]/(den[hh] + 1e-16f);
}

__global__ void conv1_fin_k(const float* __restrict__ W1, const float* __restrict__ b1,
                            const float* __restrict__ s4, unsigned short* __restrict__ hbf){
  int i = blockIdx.x*256 + threadIdx.x;
  int n = i >> 8; int c = i & 255;
  float v = W1[c]*s4[n*4 + (c>>6)] + b1[c];
  hbf[i] = f2b(gelu_f(v));
}

// ---------------- weight transpose to bf16: Wt[l][n][k] = W2[l][k][n] ----------------
__global__ void wtr_k(const float* __restrict__ W2, unsigned short* __restrict__ Wt){
  __shared__ float tile[64][65];
  int l = blockIdx.z;
  const float* B = W2 + l*DD*DD;
  unsigned short* O = Wt + l*DD*DD;
  int r0 = blockIdx.x*64, c0 = blockIdx.y*64;
  int t = threadIdx.x;
  int tr = t >> 4, tc4 = (t & 15)*4;
  #pragma unroll
  for (int i = 0; i < 4; i++){
    int r = tr + i*16;
    float4 v = *(const float4*)&B[(r0+r)*DD + c0 + tc4];
    tile[r][tc4+0]=v.x; tile[r][tc4+1]=v.y; tile[r][tc4+2]=v.z; tile[r][tc4+3]=v.w;
  }
  __syncthreads();
  #pragma unroll
  for (int i = 0; i < 4; i++){
    int c = tr + i*16;
    ushort4 o;
    o.x = f2b(tile[tc4+0][c]);
    o.y = f2b(tile[tc4+1][c]);
    o.z = f2b(tile[tc4+2][c]);
    o.w = f2b(tile[tc4+3][c]);
    *(ushort4*)&O[(c0+c)*DD + r0 + tc4] = o;
  }
}

// ---------------- bf16 MFMA GEMM: C[M,256] = A[M,256] @ Bt^T ----------------
__global__ __launch_bounds__(256) void gemm_k(const unsigned short* __restrict__ A,
                                              const unsigned short* __restrict__ Bt,
                                              float* __restrict__ C, int M){
  __shared__ unsigned short As[128][48];
  __shared__ unsigned short Bs[128][48];
  int tid = threadIdx.x;
  int lane = tid & 63, w = tid >> 6;
  int wm = w >> 1, wn = w & 1;
  int bm = blockIdx.x*128, bn = blockIdx.y*128;
  f32x4 acc[4][4] = {};
  int r = tid >> 2, cb = (tid & 3) * 8;
  for (int k0 = 0; k0 < 256; k0 += 32){
    #pragma unroll
    for (int hh = 0; hh < 2; hh++){
      int row = bm + r + hh*64;
      bf16x8 v = {};
      if (row < M) v = *(const bf16x8*)&A[row*256 + k0 + cb];
      *(bf16x8*)&As[r + hh*64][cb] = v;
      *(bf16x8*)&Bs[r + hh*64][cb] = *(const bf16x8*)&Bt[(bn + r + hh*64)*256 + k0 + cb];
    }
    __syncthreads();
    bf16x8 af[4], bfr[4];
    int kk = (lane >> 4) * 8;
    int rl = lane & 15;
    #pragma unroll
    for (int i = 0; i < 4; i++) af[i] = *(const bf16x8*)&As[wm*64 + i*16 + rl][kk];
    #pragma unroll
    for (int j = 0; j < 4; j++) bfr[j] = *(const bf16x8*)&Bs[wn*64 + j*16 + rl][kk];
    #pragma unroll
    for (int i = 0; i < 4; i++)
      #pragma unroll
      for (int j = 0; j < 4; j++)
        acc[i][j] = __builtin_amdgcn_mfma_f32_16x16x32_bf16(af[i], bfr[j], acc[i][j], 0,0,0);
    __syncthreads();
  }
  int cl = lane & 15, rg = (lane >> 4) * 4;
  #pragma unroll
  for (int i = 0; i < 4; i++){
    #pragma unroll
    for (int rr = 0; rr < 4; rr++){
      int row = bm + wm*64 + i*16 + rg + rr;
      if (row < M){
        #pragma unroll
        for (int j = 0; j < 4; j++)
          C[row*256 + bn + wn*64 + j*16 + cl] = acc[i][j][rr];
      }
    }
  }
}

// ---------------- per-node attention scalars ----------------
__global__ void asd_k(const float* __restrict__ g, const float* __restrict__ as,
                      const float* __restrict__ ad, float* __restrict__ a_s,
                      float* __restrict__ a_d){
  int gw = (blockIdx.x*256 + threadIdx.x) >> 6;
  int lane = threadIdx.x & 63;
  if (gw >= NN) return;
  const float* row = g + gw*256;
  float p = 0.f, q = 0.f;
  #pragma unroll
  for (int j = 0; j < 4; j++){
    float v = row[lane + 64*j];
    p += v*as[lane + 64*j];
    q += v*ad[lane + 64*j];
  }
  for (int ofs = 32; ofs > 0; ofs >>= 1){
    p += __shfl_down(p, ofs, 64);
    q += __shfl_down(q, ofs, 64);
  }
  if (lane == 0){ a_s[gw] = p; a_d[gw] = q; }
}

// ---------------- conv2 aggregation (block per dst node) ----------------
__global__ __launch_bounds__(256) void agg2_k(const float* __restrict__ g,
    const float* __restrict__ a_s, const float* __restrict__ a_d,
    const int* __restrict__ off, const int* __restrict__ cs, const int* __restrict__ ce,
    const float* __restrict__ b2l, unsigned short* __restrict__ hbf,
    float* __restrict__ alpha_out){
  int d = blockIdx.x;
  int t = threadIdx.x;
  int o0 = off[d], o1 = off[d+1];
  float add = a_d[d];
  float m = -1e30f;
  for (int k = o0; k < o1; k++) m = fmaxf(m, lrelu_f(a_s[cs[k]] + add));
  float den = 0.f, acc = 0.f;
  for (int k = o0; k < o1; k++){
    int s = cs[k];
    float ex = expf(lrelu_f(a_s[s] + add) - m);
    den += ex;
    acc += ex * g[s*256 + t];
  }
  float inv = 1.0f/(den + 1e-16f);
  hbf[d*256 + t] = f2b(gelu_f(acc*inv + b2l[t]));
  if (alpha_out){
    for (int k = o0 + t; k < o1; k += 256){
      int s = cs[k];
      float ex = expf(lrelu_f(a_s[s] + add) - m);
      alpha_out[ce[k]] = ex*inv;
    }
  }
}

// ---------------- pooling (sums + counts) + MLP head ----------------
__global__ void pool_k(const unsigned short* __restrict__ hbf, const int* __restrict__ batch,
                       float* __restrict__ pool, float* __restrict__ cnts){
  __shared__ float lp[NG*256];
  __shared__ float lc[NG];
  int t = threadIdx.x;
  for (int gg = 0; gg < NG; gg++) lp[gg*256 + t] = 0.f;
  if (t < NG) lc[t] = 0.f;
  __syncthreads();
  for (int n = blockIdx.x; n < NN; n += gridDim.x){
    int b = batch[n];
    lp[b*256 + t] += b2f(hbf[n*256 + t]);
    if (t == 0) lc[b] += 1.f;
  }
  __syncthreads();
  for (int gg = 0; gg < NG; gg++) atomicAdd(&pool[gg*256 + t], lp[gg*256 + t]);
  if (t < NG) atomicAdd(&cnts[t], lc[t]);
}

__global__ void mlp_k(const float* __restrict__ pool, const float* __restrict__ cnts,
                      const float* __restrict__ Wl1, const float* __restrict__ bl1,
                      const float* __restrict__ Wl2, const float* __restrict__ bl2,
                      const float* __restrict__ Wl3, const float* __restrict__ bl3,
                      float* __restrict__ out){
  __shared__ float mean[256];
  __shared__ float z1[128];
  __shared__ float z2[64];
  int g = blockIdx.x, t = threadIdx.x;
  mean[t] = pool[g*256 + t] / cnts[g];
  __syncthreads();
  if (t < 128){
    float s = bl1[t];
    for (int k = 0; k < 256; k++) s += mean[k]*Wl1[k*128 + t];
    z1[t] = gelu_f(s);
  }
  __syncthreads();
  if (t < 64){
    float s = bl2[t];
    for (int k = 0; k < 128; k++) s += z1[k]*Wl2[k*64 + t];
    z2[t] = gelu_f(s);
  }
  __syncthreads();
  if (t == 0){
    float s = bl3[0];
    for (int k = 0; k < 64; k++) s += z2[k]*Wl3[k];
    out[g] = 1.f/(1.f + expf(-s));
  }
}

__global__ void eout_k(const int* __restrict__ ei, float* __restrict__ out){
  int i = blockIdx.x*256 + threadIdx.x;
  if (i >= ET) return;
  float s, d;
  if (i < EE){ s = (float)ei[i]; d = (float)ei[EE + i]; }
  else { s = (float)(i - EE); d = s; }
  out[16 + i] = s;
  out[16 + ET + i] = d;
}

extern "C" void kernel_launch(void* const* d_in, const int* in_sizes, int n_in,
                              void* d_out, int out_size, void* d_ws, size_t ws_size,
                              hipStream_t stream) {
  const float* x   = (const float*)d_in[0];
  const int*   ei  = (const int*)d_in[1];
  const int*   batch = (const int*)d_in[2];
  const float* W1  = (const float*)d_in[3];
  const float* as1 = (const float*)d_in[4];
  const float* ad1 = (const float*)d_in[5];
  const float* b1  = (const float*)d_in[6];
  const float* W2  = (const float*)d_in[7];
  const float* as2 = (const float*)d_in[8];
  const float* ad2 = (const float*)d_in[9];
  const float* b2  = (const float*)d_in[10];
  const float* Wl1 = (const float*)d_in[11];
  const float* bl1 = (const float*)d_in[12];
  const float* Wl2 = (const float*)d_in[13];
  const float* bl2 = (const float*)d_in[14];
  const float* Wl3 = (const float*)d_in[15];
  const float* bl3 = (const float*)d_in[16];
  float* out = (float*)d_out;

  float* g    = (float*)d_ws;                        // NN*DD f32
  unsigned short* hbf = (unsigned short*)(g + NN*DD);// NN*DD bf16
  unsigned short* Wt  = hbf + NN*DD;                 // 3*DD*DD bf16
  float* a_s  = (float*)(Wt + 3*DD*DD);              // NN
  float* a_d  = a_s + NN;
  float* s4   = a_d + NN;                            // NN*NH
  float* ST   = s4  + NN*NH;                         // 8
  float* pool = ST  + 8;                             // NG*DD
  float* cnts = pool + NG*DD;                        // NG
  int* ideg   = (int*)(cnts + NG);                   // NN+1 (offsets after scan)
  int* icur   = ideg + (NN + 1);                     // NN
  int* csr_s  = icur + NN;                           // ET
  int* csr_e  = csr_s + ET;                          // ET

  hipMemsetAsync(ideg, 0, sizeof(int)*(2*NN + 1), stream);
  hipMemsetAsync(pool, 0, sizeof(float)*(NG*DD + NG), stream);

  hist_k<<<(ET + 255)/256, 256, 0, stream>>>(ei, ideg);
  scan_k<<<1, 1024, 0, stream>>>(ideg);
  scatter_k<<<(ET + 255)/256, 256, 0, stream>>>(ei, ideg, icur, csr_s, csr_e);

  wtr_k<<<dim3(4,4,3), 256, 0, stream>>>(W2, Wt);
  conv1_pre_k<<<1, 256, 0, stream>>>(W1, as1, ad1, ST);
  conv1_agg_k<<<(NN + 255)/256, 256, 0, stream>>>(x, ideg, csr_s, ST, s4);
  conv1_fin_k<<<NN, 256, 0, stream>>>(W1, b1, s4, hbf);

  for (int l = 0; l < 3; l++){
    gemm_k<<<dim3((NN + 127)/128, 2), 256, 0, stream>>>(hbf, Wt + l*DD*DD, g, NN);
    asd_k<<<(NN*64 + 255)/256, 256, 0, stream>>>(g, as2 + l*DD, ad2 + l*DD, a_s, a_d);
    agg2_k<<<NN, 256, 0, stream>>>(g, a_s, a_d, ideg, csr_s, csr_e, b2 + l*DD, hbf,
                                   (l == 2) ? (out + 16 + 2*ET) : (float*)nullptr);
  }

  pool_k<<<128, 256, 0, stream>>>(hbf, batch, pool, cnts);
  mlp_k<<<NG, 256, 0, stream>>>(pool, cnts, Wl1, bl1, Wl2, bl2, Wl3, bl3, out);
  eout_k<<<(ET + 255)/256, 256, 0, stream>>>(ei, out);
}

// Round 3
// 452.567 us; speedup vs baseline: 1.8254x; 1.1966x over previous
//
#include <hip/hip_runtime.h>
#include <hip/hip_bf16.h>
#include <math.h>

#define NN 20000
#define EE 320000
#define ET 340000   // EE + NN self loops
#define NG 16
#define DD 256
#define NH 4

typedef __attribute__((ext_vector_type(8))) short bf16x8;
typedef __attribute__((ext_vector_type(4))) float f32x4;

__device__ __forceinline__ float gelu_f(float x){
  float x3 = x*x*x;
  return 0.5f*x*(1.0f + tanhf(0.7978845608028654f*(x + 0.044715f*x3)));
}
__device__ __forceinline__ float lrelu_f(float x){ return x > 0.f ? x : 0.2f*x; }
__device__ __forceinline__ unsigned short f2b(float f){
  __hip_bfloat16 b = __float2bfloat16(f);
  return *(unsigned short*)&b;
}
__device__ __forceinline__ float b2f(unsigned short u){
  __hip_bfloat16 b; *(unsigned short*)&b = u;
  return __bfloat162float(b);
}

// ---------------- CSR build ----------------
__global__ void hist_k(const int* __restrict__ ei, int* __restrict__ deg){
  int i = blockIdx.x*256 + threadIdx.x;
  if (i >= ET) return;
  int dst = (i < EE) ? ei[EE + i] : (i - EE);
  atomicAdd(&deg[dst], 1);
}

__global__ void scan_k(int* __restrict__ deg){
  __shared__ int wsum[16];
  __shared__ int carry;
  int t = threadIdx.x, lane = t & 63, w = t >> 6;
  if (t == 0) carry = 0;
  __syncthreads();
  for (int base = 0; base < NN; base += 1024){
    int i = base + t;
    int v = (i < NN) ? deg[i] : 0;
    int s = v;
    #pragma unroll
    for (int ofs = 1; ofs < 64; ofs <<= 1){
      int u = __shfl_up(s, ofs, 64);
      if (lane >= ofs) s += u;
    }
    if (lane == 63) wsum[w] = s;
    __syncthreads();
    if (w == 0 && lane < 16){
      int ws = wsum[lane];
      #pragma unroll
      for (int ofs = 1; ofs < 16; ofs <<= 1){
        int u = __shfl_up(ws, ofs, 64);
        if (lane >= ofs) ws += u;
      }
      wsum[lane] = ws;
    }
    __syncthreads();
    int excl = s - v + (w > 0 ? wsum[w-1] : 0) + carry;
    if (i < NN) deg[i] = excl;
    __syncthreads();
    if (t == 0) carry += wsum[15];
    __syncthreads();
  }
  if (t == 0) deg[NN] = carry;
}

__global__ void scatter_k(const int* __restrict__ ei, const int* __restrict__ off,
                          int* __restrict__ cur, int* __restrict__ cs, int* __restrict__ ce){
  int i = blockIdx.x*256 + threadIdx.x;
  if (i >= ET) return;
  int src, dst;
  if (i < EE){ src = ei[i]; dst = ei[EE + i]; } else { src = i - EE; dst = src; }
  int pos = off[dst] + atomicAdd(&cur[dst], 1);
  cs[pos] = src; ce[pos] = i;
}

// ---------------- conv1 (input dim 1 -> algebraic collapse) ----------------
__global__ void conv1_pre_k(const float* __restrict__ W1, const float* __restrict__ as1,
                            const float* __restrict__ ad1, float* __restrict__ ST){
  int t = threadIdx.x;
  float w = W1[t];
  float p = w*as1[t], q = w*ad1[t];
  for (int ofs = 32; ofs > 0; ofs >>= 1){
    p += __shfl_down(p, ofs, 64);
    q += __shfl_down(q, ofs, 64);
  }
  if ((t & 63) == 0){ ST[t>>6] = p; ST[4 + (t>>6)] = q; }
}

__global__ void conv1_agg_k(const float* __restrict__ x, const int* __restrict__ off,
                            const int* __restrict__ cs, const float* __restrict__ ST,
                            float* __restrict__ s4){
  int d = blockIdx.x*256 + threadIdx.x;
  if (d >= NN) return;
  float S[4], T[4];
  #pragma unroll
  for (int hh = 0; hh < 4; hh++){ S[hh] = ST[hh]; T[hh] = ST[4+hh]; }
  float xd = x[d];
  int o0 = off[d], o1 = off[d+1];
  float m[4] = {-1e30f,-1e30f,-1e30f,-1e30f};
  for (int k = o0; k < o1; k++){
    float xs = x[cs[k]];
    #pragma unroll
    for (int hh = 0; hh < 4; hh++)
      m[hh] = fmaxf(m[hh], lrelu_f(xs*S[hh] + xd*T[hh]));
  }
  float den[4] = {0,0,0,0}, ac[4] = {0,0,0,0};
  for (int k = o0; k < o1; k++){
    float xs = x[cs[k]];
    #pragma unroll
    for (int hh = 0; hh < 4; hh++){
      float ex = expf(lrelu_f(xs*S[hh] + xd*T[hh]) - m[hh]);
      den[hh] += ex; ac[hh] += ex*xs;
    }
  }
  #pragma unroll
  for (int hh = 0; hh < 4; hh++) s4[d*4+hh] = ac[hh]/(den[hh] + 1e-16f);
}

__global__ void conv1_fin_k(const float* __restrict__ W1, const float* __restrict__ b1,
                            const float* __restrict__ s4, unsigned short* __restrict__ hbf){
  int i = blockIdx.x*256 + threadIdx.x;
  int n = i >> 8; int c = i & 255;
  float v = W1[c]*s4[n*4 + (c>>6)] + b1[c];
  hbf[i] = f2b(gelu_f(v));
}

// ---------------- weight transpose to bf16: Wt[l][n][k] = W2[l][k][n] ----------------
__global__ void wtr_k(const float* __restrict__ W2, unsigned short* __restrict__ Wt){
  __shared__ float tile[64][65];
  int l = blockIdx.z;
  const float* B = W2 + l*DD*DD;
  unsigned short* O = Wt + l*DD*DD;
  int r0 = blockIdx.x*64, c0 = blockIdx.y*64;
  int t = threadIdx.x;
  int tr = t >> 4, tc4 = (t & 15)*4;
  #pragma unroll
  for (int i = 0; i < 4; i++){
    int r = tr + i*16;
    float4 v = *(const float4*)&B[(r0+r)*DD + c0 + tc4];
    tile[r][tc4+0]=v.x; tile[r][tc4+1]=v.y; tile[r][tc4+2]=v.z; tile[r][tc4+3]=v.w;
  }
  __syncthreads();
  #pragma unroll
  for (int i = 0; i < 4; i++){
    int c = tr + i*16;
    ushort4 o;
    o.x = f2b(tile[tc4+0][c]);
    o.y = f2b(tile[tc4+1][c]);
    o.z = f2b(tile[tc4+2][c]);
    o.w = f2b(tile[tc4+3][c]);
    *(ushort4*)&O[(c0+c)*DD + r0 + tc4] = o;
  }
}

// -------- bf16 MFMA GEMM: gbf[M,256] = A@Bt^T (bf16 out) + fused a_s/a_d dots --------
__global__ __launch_bounds__(256) void gemm_k(const unsigned short* __restrict__ A,
                                              const unsigned short* __restrict__ Bt,
                                              unsigned short* __restrict__ Cb,
                                              const float* __restrict__ asv,
                                              const float* __restrict__ adv,
                                              float* __restrict__ a_s,
                                              float* __restrict__ a_d, int M){
  __shared__ unsigned short As[128][48];
  __shared__ unsigned short Bs[128][48];
  int tid = threadIdx.x;
  int lane = tid & 63, w = tid >> 6;
  int wm = w >> 1, wn = w & 1;
  int bm = blockIdx.x*128, bn = blockIdx.y*128;
  f32x4 acc[4][4] = {};
  int r = tid >> 2, cb = (tid & 3) * 8;
  for (int k0 = 0; k0 < 256; k0 += 32){
    #pragma unroll
    for (int hh = 0; hh < 2; hh++){
      int row = bm + r + hh*64;
      bf16x8 v = {};
      if (row < M) v = *(const bf16x8*)&A[row*256 + k0 + cb];
      *(bf16x8*)&As[r + hh*64][cb] = v;
      *(bf16x8*)&Bs[r + hh*64][cb] = *(const bf16x8*)&Bt[(bn + r + hh*64)*256 + k0 + cb];
    }
    __syncthreads();
    bf16x8 af[4], bfr[4];
    int kk = (lane >> 4) * 8;
    int rl = lane & 15;
    #pragma unroll
    for (int i = 0; i < 4; i++) af[i] = *(const bf16x8*)&As[wm*64 + i*16 + rl][kk];
    #pragma unroll
    for (int j = 0; j < 4; j++) bfr[j] = *(const bf16x8*)&Bs[wn*64 + j*16 + rl][kk];
    #pragma unroll
    for (int i = 0; i < 4; i++)
      #pragma unroll
      for (int j = 0; j < 4; j++)
        acc[i][j] = __builtin_amdgcn_mfma_f32_16x16x32_bf16(af[i], bfr[j], acc[i][j], 0,0,0);
    __syncthreads();
  }
  int cl = lane & 15, rg = (lane >> 4) * 4;
  float asl[4], adl[4];
  #pragma unroll
  for (int j = 0; j < 4; j++){
    int col = bn + wn*64 + j*16 + cl;
    asl[j] = asv[col]; adl[j] = adv[col];
  }
  #pragma unroll
  for (int i = 0; i < 4; i++){
    #pragma unroll
    for (int rr = 0; rr < 4; rr++){
      int row = bm + wm*64 + i*16 + rg + rr;
      if (row < M){
        float p = 0.f, q = 0.f;
        #pragma unroll
        for (int j = 0; j < 4; j++){
          float v = acc[i][j][rr];
          p += v*asl[j]; q += v*adl[j];
          Cb[row*256 + bn + wn*64 + j*16 + cl] = f2b(v);
        }
        #pragma unroll
        for (int ofs = 1; ofs < 16; ofs <<= 1){
          p += __shfl_xor(p, ofs, 64);
          q += __shfl_xor(q, ofs, 64);
        }
        if (cl == 0){
          atomicAdd(&a_s[row], p);
          atomicAdd(&a_d[row], q);
        }
      }
    }
  }
}

// ---------------- per-edge normalized attention (1 thread / dst node) ----------------
__global__ void alpha_k(const float* __restrict__ a_s, const float* __restrict__ a_d,
                        const int* __restrict__ off, const int* __restrict__ cs,
                        const int* __restrict__ ce, float* __restrict__ alf,
                        float* __restrict__ alpha_out){
  int d = blockIdx.x*256 + threadIdx.x;
  if (d >= NN) return;
  int o0 = off[d], o1 = off[d+1];
  float add = a_d[d];
  float m = -1e30f;
  for (int k = o0; k < o1; k++) m = fmaxf(m, lrelu_f(a_s[cs[k]] + add));
  float den = 0.f;
  for (int k = o0; k < o1; k++){
    float ex = expf(lrelu_f(a_s[cs[k]] + add) - m);
    den += ex; alf[k] = ex;
  }
  float inv = 1.0f/(den + 1e-16f);
  for (int k = o0; k < o1; k++){
    float v = alf[k]*inv;
    alf[k] = v;
    if (alpha_out) alpha_out[ce[k]] = v;
  }
}

// ---------------- weighted gather-sum (1 wave / dst node) ----------------
__global__ __launch_bounds__(256) void agg_k(const unsigned short* __restrict__ gbf,
    const float* __restrict__ alf, const int* __restrict__ off, const int* __restrict__ cs,
    const float* __restrict__ b2l, unsigned short* __restrict__ hbf){
  int d = (blockIdx.x*256 + threadIdx.x) >> 6;
  int lane = threadIdx.x & 63;
  if (d >= NN) return;
  int o0 = off[d], o1 = off[d+1];
  int c4 = lane*4;
  float acc0=0.f, acc1=0.f, acc2=0.f, acc3=0.f;
  for (int k = o0; k < o1; k++){
    int s = cs[k];
    float al = alf[k];
    ushort4 v = *(const ushort4*)&gbf[s*256 + c4];
    acc0 += al*b2f(v.x); acc1 += al*b2f(v.y);
    acc2 += al*b2f(v.z); acc3 += al*b2f(v.w);
  }
  ushort4 o;
  o.x = f2b(gelu_f(acc0 + b2l[c4+0]));
  o.y = f2b(gelu_f(acc1 + b2l[c4+1]));
  o.z = f2b(gelu_f(acc2 + b2l[c4+2]));
  o.w = f2b(gelu_f(acc3 + b2l[c4+3]));
  *(ushort4*)&hbf[d*256 + c4] = o;
}

// ---------------- pooling (sums + counts) + MLP head ----------------
__global__ void pool_k(const unsigned short* __restrict__ hbf, const int* __restrict__ batch,
                       float* __restrict__ pool, float* __restrict__ cnts){
  __shared__ float lp[NG*256];
  __shared__ float lc[NG];
  int t = threadIdx.x;
  for (int gg = 0; gg < NG; gg++) lp[gg*256 + t] = 0.f;
  if (t < NG) lc[t] = 0.f;
  __syncthreads();
  for (int n = blockIdx.x; n < NN; n += gridDim.x){
    int b = batch[n];
    lp[b*256 + t] += b2f(hbf[n*256 + t]);
    if (t == 0) lc[b] += 1.f;
  }
  __syncthreads();
  for (int gg = 0; gg < NG; gg++) atomicAdd(&pool[gg*256 + t], lp[gg*256 + t]);
  if (t < NG) atomicAdd(&cnts[t], lc[t]);
}

__global__ void mlp_k(const float* __restrict__ pool, const float* __restrict__ cnts,
                      const float* __restrict__ Wl1, const float* __restrict__ bl1,
                      const float* __restrict__ Wl2, const float* __restrict__ bl2,
                      const float* __restrict__ Wl3, const float* __restrict__ bl3,
                      float* __restrict__ out){
  __shared__ float mean[256];
  __shared__ float z1[128];
  __shared__ float z2[64];
  int g = blockIdx.x, t = threadIdx.x;
  mean[t] = pool[g*256 + t] / cnts[g];
  __syncthreads();
  if (t < 128){
    float s = bl1[t];
    for (int k = 0; k < 256; k++) s += mean[k]*Wl1[k*128 + t];
    z1[t] = gelu_f(s);
  }
  __syncthreads();
  if (t < 64){
    float s = bl2[t];
    for (int k = 0; k < 128; k++) s += z1[k]*Wl2[k*64 + t];
    z2[t] = gelu_f(s);
  }
  __syncthreads();
  if (t == 0){
    float s = bl3[0];
    for (int k = 0; k < 64; k++) s += z2[k]*Wl3[k];
    out[g] = 1.f/(1.f + expf(-s));
  }
}

__global__ void eout_k(const int* __restrict__ ei, float* __restrict__ out){
  int i = blockIdx.x*256 + threadIdx.x;
  if (i >= ET) return;
  float s, d;
  if (i < EE){ s = (float)ei[i]; d = (float)ei[EE + i]; }
  else { s = (float)(i - EE); d = s; }
  out[16 + i] = s;
  out[16 + ET + i] = d;
}

extern "C" void kernel_launch(void* const* d_in, const int* in_sizes, int n_in,
                              void* d_out, int out_size, void* d_ws, size_t ws_size,
                              hipStream_t stream) {
  const float* x   = (const float*)d_in[0];
  const int*   ei  = (const int*)d_in[1];
  const int*   batch = (const int*)d_in[2];
  const float* W1  = (const float*)d_in[3];
  const float* as1 = (const float*)d_in[4];
  const float* ad1 = (const float*)d_in[5];
  const float* b1  = (const float*)d_in[6];
  const float* W2  = (const float*)d_in[7];
  const float* as2 = (const float*)d_in[8];
  const float* ad2 = (const float*)d_in[9];
  const float* b2  = (const float*)d_in[10];
  const float* Wl1 = (const float*)d_in[11];
  const float* bl1 = (const float*)d_in[12];
  const float* Wl2 = (const float*)d_in[13];
  const float* bl2 = (const float*)d_in[14];
  const float* Wl3 = (const float*)d_in[15];
  const float* bl3 = (const float*)d_in[16];
  float* out = (float*)d_out;

  unsigned short* gbf = (unsigned short*)d_ws;       // NN*DD bf16
  unsigned short* hbf = gbf + NN*DD;                 // NN*DD bf16
  unsigned short* Wt  = hbf + NN*DD;                 // 3*DD*DD bf16
  float* a_s  = (float*)(Wt + 3*DD*DD);              // NN
  float* a_d  = a_s + NN;                            // NN
  float* s4   = a_d + NN;                            // NN*NH
  float* ST   = s4  + NN*NH;                         // 8
  float* pool = ST  + 8;                             // NG*DD
  float* cnts = pool + NG*DD;                        // NG
  float* alf  = cnts + NG;                           // ET
  int* ideg   = (int*)(alf + ET);                    // NN+1
  int* icur   = ideg + (NN + 1);                     // NN
  int* csr_s  = icur + NN;                           // ET
  int* csr_e  = csr_s + ET;                          // ET

  hipMemsetAsync(ideg, 0, sizeof(int)*(2*NN + 1), stream);
  hipMemsetAsync(pool, 0, sizeof(float)*(NG*DD + NG), stream);

  hist_k<<<(ET + 255)/256, 256, 0, stream>>>(ei, ideg);
  scan_k<<<1, 1024, 0, stream>>>(ideg);
  scatter_k<<<(ET + 255)/256, 256, 0, stream>>>(ei, ideg, icur, csr_s, csr_e);

  wtr_k<<<dim3(4,4,3), 256, 0, stream>>>(W2, Wt);
  conv1_pre_k<<<1, 256, 0, stream>>>(W1, as1, ad1, ST);
  conv1_agg_k<<<(NN + 255)/256, 256, 0, stream>>>(x, ideg, csr_s, ST, s4);
  conv1_fin_k<<<NN, 256, 0, stream>>>(W1, b1, s4, hbf);

  for (int l = 0; l < 3; l++){
    hipMemsetAsync(a_s, 0, sizeof(float)*2*NN, stream);
    gemm_k<<<dim3((NN + 127)/128, 2), 256, 0, stream>>>(hbf, Wt + l*DD*DD, gbf,
                                                        as2 + l*DD, ad2 + l*DD, a_s, a_d, NN);
    alpha_k<<<(NN + 255)/256, 256, 0, stream>>>(a_s, a_d, ideg, csr_s, csr_e, alf,
                                                (l == 2) ? (out + 16 + 2*ET) : (float*)nullptr);
    agg_k<<<(NN*64 + 255)/256, 256, 0, stream>>>(gbf, alf, ideg, csr_s, b2 + l*DD, hbf);
  }

  pool_k<<<128, 256, 0, stream>>>(hbf, batch, pool, cnts);
  mlp_k<<<NG, 256, 0, stream>>>(pool, cnts, Wl1, bl1, Wl2, bl2, Wl3, bl3, out);
  eout_k<<<(ET + 255)/256, 256, 0, stream>>>(ei, out);
}

// Round 4
// 361.674 us; speedup vs baseline: 2.2842x; 1.2513x over previous
//
#include <hip/hip_runtime.h>
#include <hip/hip_bf16.h>
#include <math.h>

#define NN 20000
#define EE 320000
#define ET 340000   // EE + NN self loops
#define NG 16
#define DD 256
#define NH 4
#define PBLK 32

typedef __attribute__((ext_vector_type(8))) short bf16x8;
typedef __attribute__((ext_vector_type(4))) float f32x4;

__device__ __forceinline__ float gelu_f(float x){
  float x3 = x*x*x;
  return 0.5f*x*(1.0f + tanhf(0.7978845608028654f*(x + 0.044715f*x3)));
}
__device__ __forceinline__ float lrelu_f(float x){ return x > 0.f ? x : 0.2f*x; }
__device__ __forceinline__ unsigned short f2b(float f){
  __hip_bfloat16 b = __float2bfloat16(f);
  return *(unsigned short*)&b;
}
__device__ __forceinline__ float b2f(unsigned short u){
  __hip_bfloat16 b; *(unsigned short*)&b = u;
  return __bfloat162float(b);
}

// ---------------- CSR build ----------------
__global__ void hist_k(const int* __restrict__ ei, int* __restrict__ deg){
  int i = blockIdx.x*256 + threadIdx.x;
  if (i >= ET) return;
  int dst = (i < EE) ? ei[EE + i] : (i - EE);
  atomicAdd(&deg[dst], 1);
}

__global__ void scan_k(int* __restrict__ deg){
  __shared__ int wsum[16];
  __shared__ int carry;
  int t = threadIdx.x, lane = t & 63, w = t >> 6;
  if (t == 0) carry = 0;
  __syncthreads();
  for (int base = 0; base < NN; base += 1024){
    int i = base + t;
    int v = (i < NN) ? deg[i] : 0;
    int s = v;
    #pragma unroll
    for (int ofs = 1; ofs < 64; ofs <<= 1){
      int u = __shfl_up(s, ofs, 64);
      if (lane >= ofs) s += u;
    }
    if (lane == 63) wsum[w] = s;
    __syncthreads();
    if (w == 0 && lane < 16){
      int ws = wsum[lane];
      #pragma unroll
      for (int ofs = 1; ofs < 16; ofs <<= 1){
        int u = __shfl_up(ws, ofs, 64);
        if (lane >= ofs) ws += u;
      }
      wsum[lane] = ws;
    }
    __syncthreads();
    int excl = s - v + (w > 0 ? wsum[w-1] : 0) + carry;
    if (i < NN) deg[i] = excl;
    __syncthreads();
    if (t == 0) carry += wsum[15];
    __syncthreads();
  }
  if (t == 0) deg[NN] = carry;
}

__global__ void scatter_k(const int* __restrict__ ei, const int* __restrict__ off,
                          int* __restrict__ cur, int* __restrict__ cs, int* __restrict__ ce){
  int i = blockIdx.x*256 + threadIdx.x;
  if (i >= ET) return;
  int src, dst;
  if (i < EE){ src = ei[i]; dst = ei[EE + i]; } else { src = i - EE; dst = src; }
  int pos = off[dst] + atomicAdd(&cur[dst], 1);
  cs[pos] = src; ce[pos] = i;
}

// ---------------- conv1 (input dim 1 -> algebraic collapse) ----------------
__global__ void conv1_pre_k(const float* __restrict__ W1, const float* __restrict__ as1,
                            const float* __restrict__ ad1, float* __restrict__ ST){
  int t = threadIdx.x;
  float w = W1[t];
  float p = w*as1[t], q = w*ad1[t];
  for (int ofs = 32; ofs > 0; ofs >>= 1){
    p += __shfl_down(p, ofs, 64);
    q += __shfl_down(q, ofs, 64);
  }
  if ((t & 63) == 0){ ST[t>>6] = p; ST[4 + (t>>6)] = q; }
}

__global__ void conv1_agg_k(const float* __restrict__ x, const int* __restrict__ off,
                            const int* __restrict__ cs, const float* __restrict__ ST,
                            float* __restrict__ s4){
  int d = blockIdx.x*256 + threadIdx.x;
  if (d >= NN) return;
  float S[4], T[4];
  #pragma unroll
  for (int hh = 0; hh < 4; hh++){ S[hh] = ST[hh]; T[hh] = ST[4+hh]; }
  float xd = x[d];
  int o0 = off[d], o1 = off[d+1];
  float m[4] = {-1e30f,-1e30f,-1e30f,-1e30f};
  for (int k = o0; k < o1; k++){
    float xs = x[cs[k]];
    #pragma unroll
    for (int hh = 0; hh < 4; hh++)
      m[hh] = fmaxf(m[hh], lrelu_f(xs*S[hh] + xd*T[hh]));
  }
  float den[4] = {0,0,0,0}, ac[4] = {0,0,0,0};
  for (int k = o0; k < o1; k++){
    float xs = x[cs[k]];
    #pragma unroll
    for (int hh = 0; hh < 4; hh++){
      float ex = expf(lrelu_f(xs*S[hh] + xd*T[hh]) - m[hh]);
      den[hh] += ex; ac[hh] += ex*xs;
    }
  }
  #pragma unroll
  for (int hh = 0; hh < 4; hh++) s4[d*4+hh] = ac[hh]/(den[hh] + 1e-16f);
}

__global__ void conv1_fin_k(const float* __restrict__ W1, const float* __restrict__ b1,
                            const float* __restrict__ s4, unsigned short* __restrict__ hbf){
  int i = blockIdx.x*256 + threadIdx.x;
  int n = i >> 8; int c = i & 255;
  float v = W1[c]*s4[n*4 + (c>>6)] + b1[c];
  hbf[i] = f2b(gelu_f(v));
}

// ---------------- weight transpose to bf16: Wt[l][n][k] = W2[l][k][n] ----------------
__global__ void wtr_k(const float* __restrict__ W2, unsigned short* __restrict__ Wt){
  __shared__ float tile[64][65];
  int l = blockIdx.z;
  const float* B = W2 + l*DD*DD;
  unsigned short* O = Wt + l*DD*DD;
  int r0 = blockIdx.x*64, c0 = blockIdx.y*64;
  int t = threadIdx.x;
  int tr = t >> 4, tc4 = (t & 15)*4;
  #pragma unroll
  for (int i = 0; i < 4; i++){
    int r = tr + i*16;
    float4 v = *(const float4*)&B[(r0+r)*DD + c0 + tc4];
    tile[r][tc4+0]=v.x; tile[r][tc4+1]=v.y; tile[r][tc4+2]=v.z; tile[r][tc4+3]=v.w;
  }
  __syncthreads();
  #pragma unroll
  for (int i = 0; i < 4; i++){
    int c = tr + i*16;
    ushort4 o;
    o.x = f2b(tile[tc4+0][c]);
    o.y = f2b(tile[tc4+1][c]);
    o.z = f2b(tile[tc4+2][c]);
    o.w = f2b(tile[tc4+3][c]);
    *(ushort4*)&O[(c0+c)*DD + r0 + tc4] = o;
  }
}

// -------- bf16 MFMA GEMM: gbf[M,256] = A@Bt^T (bf16 out) + fused a_s/a_d dots --------
__global__ __launch_bounds__(256) void gemm_k(const unsigned short* __restrict__ A,
                                              const unsigned short* __restrict__ Bt,
                                              unsigned short* __restrict__ Cb,
                                              const float* __restrict__ asv,
                                              const float* __restrict__ adv,
                                              float* __restrict__ a_s,
                                              float* __restrict__ a_d, int M){
  __shared__ unsigned short As[128][48];
  __shared__ unsigned short Bs[128][48];
  int tid = threadIdx.x;
  int lane = tid & 63, w = tid >> 6;
  int wm = w >> 1, wn = w & 1;
  int bm = blockIdx.x*128, bn = blockIdx.y*128;
  f32x4 acc[4][4] = {};
  int r = tid >> 2, cb = (tid & 3) * 8;
  for (int k0 = 0; k0 < 256; k0 += 32){
    #pragma unroll
    for (int hh = 0; hh < 2; hh++){
      int row = bm + r + hh*64;
      bf16x8 v = {};
      if (row < M) v = *(const bf16x8*)&A[row*256 + k0 + cb];
      *(bf16x8*)&As[r + hh*64][cb] = v;
      *(bf16x8*)&Bs[r + hh*64][cb] = *(const bf16x8*)&Bt[(bn + r + hh*64)*256 + k0 + cb];
    }
    __syncthreads();
    bf16x8 af[4], bfr[4];
    int kk = (lane >> 4) * 8;
    int rl = lane & 15;
    #pragma unroll
    for (int i = 0; i < 4; i++) af[i] = *(const bf16x8*)&As[wm*64 + i*16 + rl][kk];
    #pragma unroll
    for (int j = 0; j < 4; j++) bfr[j] = *(const bf16x8*)&Bs[wn*64 + j*16 + rl][kk];
    #pragma unroll
    for (int i = 0; i < 4; i++)
      #pragma unroll
      for (int j = 0; j < 4; j++)
        acc[i][j] = __builtin_amdgcn_mfma_f32_16x16x32_bf16(af[i], bfr[j], acc[i][j], 0,0,0);
    __syncthreads();
  }
  int cl = lane & 15, rg = (lane >> 4) * 4;
  float asl[4], adl[4];
  #pragma unroll
  for (int j = 0; j < 4; j++){
    int col = bn + wn*64 + j*16 + cl;
    asl[j] = asv[col]; adl[j] = adv[col];
  }
  #pragma unroll
  for (int i = 0; i < 4; i++){
    #pragma unroll
    for (int rr = 0; rr < 4; rr++){
      int row = bm + wm*64 + i*16 + rg + rr;
      if (row < M){
        float p = 0.f, q = 0.f;
        #pragma unroll
        for (int j = 0; j < 4; j++){
          float v = acc[i][j][rr];
          p += v*asl[j]; q += v*adl[j];
          Cb[row*256 + bn + wn*64 + j*16 + cl] = f2b(v);
        }
        #pragma unroll
        for (int ofs = 1; ofs < 16; ofs <<= 1){
          p += __shfl_xor(p, ofs, 64);
          q += __shfl_xor(q, ofs, 64);
        }
        if (cl == 0){
          atomicAdd(&a_s[row], p);
          atomicAdd(&a_d[row], q);
        }
      }
    }
  }
}

// -------- per-edge normalized attention (1 wave / dst node) --------
__global__ __launch_bounds__(256) void alpha_k(const float* __restrict__ a_s,
                        const float* __restrict__ a_d,
                        const int* __restrict__ off, const int* __restrict__ cs,
                        const int* __restrict__ ce, float* __restrict__ alf,
                        float* __restrict__ alpha_out){
  int d = (blockIdx.x*256 + threadIdx.x) >> 6;
  int lane = threadIdx.x & 63;
  if (d >= NN) return;
  int o0 = off[d], o1 = off[d+1];
  float add = a_d[d];
  float m = -1e30f;
  for (int k = o0 + lane; k < o1; k += 64)
    m = fmaxf(m, lrelu_f(a_s[cs[k]] + add));
  #pragma unroll
  for (int ofs = 32; ofs > 0; ofs >>= 1) m = fmaxf(m, __shfl_xor(m, ofs, 64));
  float den = 0.f;
  for (int k = o0 + lane; k < o1; k += 64){
    float ex = expf(lrelu_f(a_s[cs[k]] + add) - m);
    den += ex; alf[k] = ex;
  }
  #pragma unroll
  for (int ofs = 32; ofs > 0; ofs >>= 1) den += __shfl_xor(den, ofs, 64);
  float inv = 1.0f/(den + 1e-16f);
  for (int k = o0 + lane; k < o1; k += 64){
    float v = alf[k]*inv;
    alf[k] = v;
    if (alpha_out) alpha_out[ce[k]] = v;
  }
}

// ---------------- weighted gather-sum (1 wave / dst node) ----------------
__global__ __launch_bounds__(256) void agg_k(const unsigned short* __restrict__ gbf,
    const float* __restrict__ alf, const int* __restrict__ off, const int* __restrict__ cs,
    const float* __restrict__ b2l, unsigned short* __restrict__ hbf){
  int d = (blockIdx.x*256 + threadIdx.x) >> 6;
  int lane = threadIdx.x & 63;
  if (d >= NN) return;
  int o0 = off[d], o1 = off[d+1];
  int c4 = lane*4;
  float acc0=0.f, acc1=0.f, acc2=0.f, acc3=0.f;
  for (int k = o0; k < o1; k++){
    int s = cs[k];
    float al = alf[k];
    ushort4 v = *(const ushort4*)&gbf[s*256 + c4];
    acc0 += al*b2f(v.x); acc1 += al*b2f(v.y);
    acc2 += al*b2f(v.z); acc3 += al*b2f(v.w);
  }
  ushort4 o;
  o.x = f2b(gelu_f(acc0 + b2l[c4+0]));
  o.y = f2b(gelu_f(acc1 + b2l[c4+1]));
  o.z = f2b(gelu_f(acc2 + b2l[c4+2]));
  o.w = f2b(gelu_f(acc3 + b2l[c4+3]));
  *(ushort4*)&hbf[d*256 + c4] = o;
}

// ---------------- pooling: contiguous chunks, register accumulate ----------------
__global__ void pool_k(const unsigned short* __restrict__ hbf, const int* __restrict__ batch,
                       float* __restrict__ pool, float* __restrict__ cnts){
  int t = threadIdx.x;
  int n0 = blockIdx.x*PBLK;
  if (n0 >= NN) return;
  int n1 = n0 + PBLK; if (n1 > NN) n1 = NN;
  float acc = 0.f;
  int cur = batch[n0], cnt = 0;
  for (int n = n0; n < n1; n++){
    int b = batch[n];
    if (b != cur){
      atomicAdd(&pool[cur*256 + t], acc);
      if (t == 0) atomicAdd(&cnts[cur], (float)cnt);
      acc = 0.f; cnt = 0; cur = b;
    }
    acc += b2f(hbf[n*256 + t]);
    cnt++;
  }
  atomicAdd(&pool[cur*256 + t], acc);
  if (t == 0) atomicAdd(&cnts[cur], (float)cnt);
}

__global__ void mlp_k(const float* __restrict__ pool, const float* __restrict__ cnts,
                      const float* __restrict__ Wl1, const float* __restrict__ bl1,
                      const float* __restrict__ Wl2, const float* __restrict__ bl2,
                      const float* __restrict__ Wl3, const float* __restrict__ bl3,
                      float* __restrict__ out){
  __shared__ float mean[256];
  __shared__ float z1[128];
  __shared__ float z2[64];
  int g = blockIdx.x, t = threadIdx.x;
  mean[t] = pool[g*256 + t] / cnts[g];
  __syncthreads();
  if (t < 128){
    float s = bl1[t];
    for (int k = 0; k < 256; k++) s += mean[k]*Wl1[k*128 + t];
    z1[t] = gelu_f(s);
  }
  __syncthreads();
  if (t < 64){
    float s = bl2[t];
    for (int k = 0; k < 128; k++) s += z1[k]*Wl2[k*64 + t];
    z2[t] = gelu_f(s);
  }
  __syncthreads();
  if (t == 0){
    float s = bl3[0];
    for (int k = 0; k < 64; k++) s += z2[k]*Wl3[k];
    out[g] = 1.f/(1.f + expf(-s));
  }
}

__global__ void eout_k(const int* __restrict__ ei, float* __restrict__ out){
  int i = blockIdx.x*256 + threadIdx.x;
  if (i >= ET) return;
  float s, d;
  if (i < EE){ s = (float)ei[i]; d = (float)ei[EE + i]; }
  else { s = (float)(i - EE); d = s; }
  out[16 + i] = s;
  out[16 + ET + i] = d;
}

extern "C" void kernel_launch(void* const* d_in, const int* in_sizes, int n_in,
                              void* d_out, int out_size, void* d_ws, size_t ws_size,
                              hipStream_t stream) {
  const float* x   = (const float*)d_in[0];
  const int*   ei  = (const int*)d_in[1];
  const int*   batch = (const int*)d_in[2];
  const float* W1  = (const float*)d_in[3];
  const float* as1 = (const float*)d_in[4];
  const float* ad1 = (const float*)d_in[5];
  const float* b1  = (const float*)d_in[6];
  const float* W2  = (const float*)d_in[7];
  const float* as2 = (const float*)d_in[8];
  const float* ad2 = (const float*)d_in[9];
  const float* b2  = (const float*)d_in[10];
  const float* Wl1 = (const float*)d_in[11];
  const float* bl1 = (const float*)d_in[12];
  const float* Wl2 = (const float*)d_in[13];
  const float* bl2 = (const float*)d_in[14];
  const float* Wl3 = (const float*)d_in[15];
  const float* bl3 = (const float*)d_in[16];
  float* out = (float*)d_out;

  unsigned short* gbf = (unsigned short*)d_ws;       // NN*DD bf16
  unsigned short* hbf = gbf + NN*DD;                 // NN*DD bf16
  unsigned short* Wt  = hbf + NN*DD;                 // 3*DD*DD bf16
  float* a_s  = (float*)(Wt + 3*DD*DD);              // NN
  float* a_d  = a_s + NN;                            // NN
  float* s4   = a_d + NN;                            // NN*NH
  float* ST   = s4  + NN*NH;                         // 8
  float* pool = ST  + 8;                             // NG*DD
  float* cnts = pool + NG*DD;                        // NG
  float* alf  = cnts + NG;                           // ET
  int* ideg   = (int*)(alf + ET);                    // NN+1
  int* icur   = ideg + (NN + 1);                     // NN
  int* csr_s  = icur + NN;                           // ET
  int* csr_e  = csr_s + ET;                          // ET

  hipMemsetAsync(ideg, 0, sizeof(int)*(2*NN + 1), stream);
  hipMemsetAsync(pool, 0, sizeof(float)*(NG*DD + NG), stream);

  hist_k<<<(ET + 255)/256, 256, 0, stream>>>(ei, ideg);
  scan_k<<<1, 1024, 0, stream>>>(ideg);
  scatter_k<<<(ET + 255)/256, 256, 0, stream>>>(ei, ideg, icur, csr_s, csr_e);

  wtr_k<<<dim3(4,4,3), 256, 0, stream>>>(W2, Wt);
  conv1_pre_k<<<1, 256, 0, stream>>>(W1, as1, ad1, ST);
  conv1_agg_k<<<(NN + 255)/256, 256, 0, stream>>>(x, ideg, csr_s, ST, s4);
  conv1_fin_k<<<NN, 256, 0, stream>>>(W1, b1, s4, hbf);

  for (int l = 0; l < 3; l++){
    hipMemsetAsync(a_s, 0, sizeof(float)*2*NN, stream);
    gemm_k<<<dim3((NN + 127)/128, 2), 256, 0, stream>>>(hbf, Wt + l*DD*DD, gbf,
                                                        as2 + l*DD, ad2 + l*DD, a_s, a_d, NN);
    alpha_k<<<(NN*64 + 255)/256, 256, 0, stream>>>(a_s, a_d, ideg, csr_s, csr_e, alf,
                                                (l == 2) ? (out + 16 + 2*ET) : (float*)nullptr);
    agg_k<<<(NN*64 + 255)/256, 256, 0, stream>>>(gbf, alf, ideg, csr_s, b2 + l*DD, hbf);
  }

  pool_k<<<(NN + PBLK - 1)/PBLK, 256, 0, stream>>>(hbf, batch, pool, cnts);
  mlp_k<<<NG, 256, 0, stream>>>(pool, cnts, Wl1, bl1, Wl2, bl2, Wl3, bl3, out);
  eout_k<<<(ET + 255)/256, 256, 0, stream>>>(ei, out);
}

// Round 5
// 286.625 us; speedup vs baseline: 2.8822x; 1.2618x over previous
//
#include <hip/hip_runtime.h>
#include <hip/hip_bf16.h>
#include <math.h>

#define NN 20000
#define EE 320000
#define ET 340000   // EE + NN self loops
#define NG 16
#define DD 256
#define NH 4
#define PBLK 32

typedef __attribute__((ext_vector_type(8))) short bf16x8;
typedef __attribute__((ext_vector_type(4))) float f32x4;

__device__ __forceinline__ float gelu_f(float x){
  float x3 = x*x*x;
  return 0.5f*x*(1.0f + tanhf(0.7978845608028654f*(x + 0.044715f*x3)));
}
__device__ __forceinline__ float lrelu_f(float x){ return x > 0.f ? x : 0.2f*x; }
__device__ __forceinline__ unsigned short f2b(float f){
  __hip_bfloat16 b = __float2bfloat16(f);
  return *(unsigned short*)&b;
}
__device__ __forceinline__ float b2f(unsigned short u){
  __hip_bfloat16 b; *(unsigned short*)&b = u;
  return __bfloat162float(b);
}

// ---------------- CSR build ----------------
__global__ void hist_k(const int* __restrict__ ei, int* __restrict__ deg){
  int i = blockIdx.x*256 + threadIdx.x;
  if (i >= ET) return;
  int dst = (i < EE) ? ei[EE + i] : (i - EE);
  atomicAdd(&deg[dst], 1);
}

__global__ void scan_k(int* __restrict__ deg){
  __shared__ int wsum[16];
  __shared__ int carry;
  int t = threadIdx.x, lane = t & 63, w = t >> 6;
  if (t == 0) carry = 0;
  __syncthreads();
  for (int base = 0; base < NN; base += 1024){
    int i = base + t;
    int v = (i < NN) ? deg[i] : 0;
    int s = v;
    #pragma unroll
    for (int ofs = 1; ofs < 64; ofs <<= 1){
      int u = __shfl_up(s, ofs, 64);
      if (lane >= ofs) s += u;
    }
    if (lane == 63) wsum[w] = s;
    __syncthreads();
    if (w == 0 && lane < 16){
      int ws = wsum[lane];
      #pragma unroll
      for (int ofs = 1; ofs < 16; ofs <<= 1){
        int u = __shfl_up(ws, ofs, 64);
        if (lane >= ofs) ws += u;
      }
      wsum[lane] = ws;
    }
    __syncthreads();
    int excl = s - v + (w > 0 ? wsum[w-1] : 0) + carry;
    if (i < NN) deg[i] = excl;
    __syncthreads();
    if (t == 0) carry += wsum[15];
    __syncthreads();
  }
  if (t == 0) deg[NN] = carry;
}

__global__ void scatter_k(const int* __restrict__ ei, const int* __restrict__ off,
                          int* __restrict__ cur, int* __restrict__ cs, int* __restrict__ ce){
  int i = blockIdx.x*256 + threadIdx.x;
  if (i >= ET) return;
  int src, dst;
  if (i < EE){ src = ei[i]; dst = ei[EE + i]; } else { src = i - EE; dst = src; }
  int pos = off[dst] + atomicAdd(&cur[dst], 1);
  cs[pos] = src; ce[pos] = i;
}

// ---------------- conv1 (input dim 1 -> algebraic collapse), 1 wave/dst ----------------
__global__ void conv1_pre_k(const float* __restrict__ W1, const float* __restrict__ as1,
                            const float* __restrict__ ad1, float* __restrict__ ST){
  int t = threadIdx.x;
  float w = W1[t];
  float p = w*as1[t], q = w*ad1[t];
  for (int ofs = 32; ofs > 0; ofs >>= 1){
    p += __shfl_down(p, ofs, 64);
    q += __shfl_down(q, ofs, 64);
  }
  if ((t & 63) == 0){ ST[t>>6] = p; ST[4 + (t>>6)] = q; }
}

__global__ __launch_bounds__(256) void conv1_agg_k(const float* __restrict__ x,
                            const int* __restrict__ off,
                            const int* __restrict__ cs, const float* __restrict__ ST,
                            float* __restrict__ s4){
  int d = (blockIdx.x*256 + threadIdx.x) >> 6;
  int lane = threadIdx.x & 63;
  if (d >= NN) return;
  float S[4], T[4];
  #pragma unroll
  for (int hh = 0; hh < 4; hh++){ S[hh] = ST[hh]; T[hh] = ST[4+hh]; }
  float xd = x[d];
  int o0 = off[d], o1 = off[d+1];
  float m[4] = {-1e30f,-1e30f,-1e30f,-1e30f};
  for (int k = o0 + lane; k < o1; k += 64){
    float xs = x[cs[k]];
    #pragma unroll
    for (int hh = 0; hh < 4; hh++)
      m[hh] = fmaxf(m[hh], lrelu_f(xs*S[hh] + xd*T[hh]));
  }
  #pragma unroll
  for (int hh = 0; hh < 4; hh++)
    #pragma unroll
    for (int ofs = 32; ofs > 0; ofs >>= 1) m[hh] = fmaxf(m[hh], __shfl_xor(m[hh], ofs, 64));
  float den[4] = {0,0,0,0}, ac[4] = {0,0,0,0};
  for (int k = o0 + lane; k < o1; k += 64){
    float xs = x[cs[k]];
    #pragma unroll
    for (int hh = 0; hh < 4; hh++){
      float ex = expf(lrelu_f(xs*S[hh] + xd*T[hh]) - m[hh]);
      den[hh] += ex; ac[hh] += ex*xs;
    }
  }
  #pragma unroll
  for (int hh = 0; hh < 4; hh++){
    #pragma unroll
    for (int ofs = 32; ofs > 0; ofs >>= 1){
      den[hh] += __shfl_xor(den[hh], ofs, 64);
      ac[hh]  += __shfl_xor(ac[hh], ofs, 64);
    }
  }
  if (lane == 0){
    #pragma unroll
    for (int hh = 0; hh < 4; hh++) s4[d*4+hh] = ac[hh]/(den[hh] + 1e-16f);
  }
}

__global__ void conv1_fin_k(const float* __restrict__ W1, const float* __restrict__ b1,
                            const float* __restrict__ s4, unsigned short* __restrict__ hbf){
  int i = blockIdx.x*256 + threadIdx.x;
  int n = i >> 8; int c = i & 255;
  float v = W1[c]*s4[n*4 + (c>>6)] + b1[c];
  hbf[i] = f2b(gelu_f(v));
}

// ---------------- weight transpose to bf16: Wt[l][n][k] = W2[l][k][n] ----------------
__global__ void wtr_k(const float* __restrict__ W2, unsigned short* __restrict__ Wt){
  __shared__ float tile[64][65];
  int l = blockIdx.z;
  const float* B = W2 + l*DD*DD;
  unsigned short* O = Wt + l*DD*DD;
  int r0 = blockIdx.x*64, c0 = blockIdx.y*64;
  int t = threadIdx.x;
  int tr = t >> 4, tc4 = (t & 15)*4;
  #pragma unroll
  for (int i = 0; i < 4; i++){
    int r = tr + i*16;
    float4 v = *(const float4*)&B[(r0+r)*DD + c0 + tc4];
    tile[r][tc4+0]=v.x; tile[r][tc4+1]=v.y; tile[r][tc4+2]=v.z; tile[r][tc4+3]=v.w;
  }
  __syncthreads();
  #pragma unroll
  for (int i = 0; i < 4; i++){
    int c = tr + i*16;
    ushort4 o;
    o.x = f2b(tile[tc4+0][c]);
    o.y = f2b(tile[tc4+1][c]);
    o.z = f2b(tile[tc4+2][c]);
    o.w = f2b(tile[tc4+3][c]);
    *(ushort4*)&O[(c0+c)*DD + r0 + tc4] = o;
  }
}

// -------- bf16 MFMA GEMM: gbf[M,256] = A@Bt^T (bf16 out) + fused a_s/a_d dots --------
__global__ __launch_bounds__(256) void gemm_k(const unsigned short* __restrict__ A,
                                              const unsigned short* __restrict__ Bt,
                                              unsigned short* __restrict__ Cb,
                                              const float* __restrict__ asv,
                                              const float* __restrict__ adv,
                                              float* __restrict__ a_s,
                                              float* __restrict__ a_d, int M){
  __shared__ unsigned short As[128][48];
  __shared__ unsigned short Bs[128][48];
  int tid = threadIdx.x;
  int lane = tid & 63, w = tid >> 6;
  int wm = w >> 1, wn = w & 1;
  int bm = blockIdx.x*128, bn = blockIdx.y*128;
  f32x4 acc[4][4] = {};
  int r = tid >> 2, cb = (tid & 3) * 8;
  for (int k0 = 0; k0 < 256; k0 += 32){
    #pragma unroll
    for (int hh = 0; hh < 2; hh++){
      int row = bm + r + hh*64;
      bf16x8 v = {};
      if (row < M) v = *(const bf16x8*)&A[row*256 + k0 + cb];
      *(bf16x8*)&As[r + hh*64][cb] = v;
      *(bf16x8*)&Bs[r + hh*64][cb] = *(const bf16x8*)&Bt[(bn + r + hh*64)*256 + k0 + cb];
    }
    __syncthreads();
    bf16x8 af[4], bfr[4];
    int kk = (lane >> 4) * 8;
    int rl = lane & 15;
    #pragma unroll
    for (int i = 0; i < 4; i++) af[i] = *(const bf16x8*)&As[wm*64 + i*16 + rl][kk];
    #pragma unroll
    for (int j = 0; j < 4; j++) bfr[j] = *(const bf16x8*)&Bs[wn*64 + j*16 + rl][kk];
    #pragma unroll
    for (int i = 0; i < 4; i++)
      #pragma unroll
      for (int j = 0; j < 4; j++)
        acc[i][j] = __builtin_amdgcn_mfma_f32_16x16x32_bf16(af[i], bfr[j], acc[i][j], 0,0,0);
    __syncthreads();
  }
  int cl = lane & 15, rg = (lane >> 4) * 4;
  float asl[4], adl[4];
  #pragma unroll
  for (int j = 0; j < 4; j++){
    int col = bn + wn*64 + j*16 + cl;
    asl[j] = asv[col]; adl[j] = adv[col];
  }
  #pragma unroll
  for (int i = 0; i < 4; i++){
    #pragma unroll
    for (int rr = 0; rr < 4; rr++){
      int row = bm + wm*64 + i*16 + rg + rr;
      if (row < M){
        float p = 0.f, q = 0.f;
        #pragma unroll
        for (int j = 0; j < 4; j++){
          float v = acc[i][j][rr];
          p += v*asl[j]; q += v*adl[j];
          Cb[row*256 + bn + wn*64 + j*16 + cl] = f2b(v);
        }
        #pragma unroll
        for (int ofs = 1; ofs < 16; ofs <<= 1){
          p += __shfl_xor(p, ofs, 64);
          q += __shfl_xor(q, ofs, 64);
        }
        if (cl == 0){
          atomicAdd(&a_s[row], p);
          atomicAdd(&a_d[row], q);
        }
      }
    }
  }
}

// ------- fused softmax + weighted gather-sum (1 wave / dst node) -------
__global__ __launch_bounds__(256) void aggf_k(const unsigned short* __restrict__ gbf,
    const float* __restrict__ a_s, const float* __restrict__ a_d,
    const int* __restrict__ off, const int* __restrict__ cs, const int* __restrict__ ce,
    const float* __restrict__ b2l, unsigned short* __restrict__ hbf,
    float* __restrict__ alpha_out){
  int d = (blockIdx.x*256 + threadIdx.x) >> 6;
  int lane = threadIdx.x & 63;
  if (d >= NN) return;
  int o0 = off[d], o1 = off[d+1];
  float add = a_d[d];
  // pass 1: max
  float m = -1e30f;
  for (int k = o0 + lane; k < o1; k += 64)
    m = fmaxf(m, lrelu_f(a_s[cs[k]] + add));
  #pragma unroll
  for (int ofs = 32; ofs > 0; ofs >>= 1) m = fmaxf(m, __shfl_xor(m, ofs, 64));
  // pass 2: denom
  float den = 0.f;
  for (int k = o0 + lane; k < o1; k += 64)
    den += expf(lrelu_f(a_s[cs[k]] + add) - m);
  #pragma unroll
  for (int ofs = 32; ofs > 0; ofs >>= 1) den += __shfl_xor(den, ofs, 64);
  float inv = 1.0f/(den + 1e-16f);
  // pass 3: chunked broadcast + 4x-unrolled gather
  int c4 = lane*4;
  const unsigned short* gp = gbf + c4;
  float acc0=0.f, acc1=0.f, acc2=0.f, acc3=0.f;
  for (int base = o0; base < o1; base += 64){
    int k = base + lane;
    float al = 0.f; int s = 0;
    if (k < o1){
      s = cs[k];
      al = expf(lrelu_f(a_s[s] + add) - m)*inv;
      if (alpha_out) alpha_out[ce[k]] = al;
    }
    int cnt = min(64, o1 - base);
    int kk = 0;
    for (; kk + 4 <= cnt; kk += 4){
      float al0=__shfl(al,kk,64),   al1=__shfl(al,kk+1,64);
      float al2=__shfl(al,kk+2,64), al3=__shfl(al,kk+3,64);
      int   s0 =__shfl(s,kk,64),    s1 =__shfl(s,kk+1,64);
      int   s2 =__shfl(s,kk+2,64),  s3 =__shfl(s,kk+3,64);
      ushort4 v0 = *(const ushort4*)&gp[s0*256];
      ushort4 v1 = *(const ushort4*)&gp[s1*256];
      ushort4 v2 = *(const ushort4*)&gp[s2*256];
      ushort4 v3 = *(const ushort4*)&gp[s3*256];
      acc0 += al0*b2f(v0.x) + al1*b2f(v1.x) + al2*b2f(v2.x) + al3*b2f(v3.x);
      acc1 += al0*b2f(v0.y) + al1*b2f(v1.y) + al2*b2f(v2.y) + al3*b2f(v3.y);
      acc2 += al0*b2f(v0.z) + al1*b2f(v1.z) + al2*b2f(v2.z) + al3*b2f(v3.z);
      acc3 += al0*b2f(v0.w) + al1*b2f(v1.w) + al2*b2f(v2.w) + al3*b2f(v3.w);
    }
    for (; kk < cnt; kk++){
      float alb = __shfl(al, kk, 64);
      int   sb  = __shfl(s, kk, 64);
      ushort4 v = *(const ushort4*)&gp[sb*256];
      acc0 += alb*b2f(v.x); acc1 += alb*b2f(v.y);
      acc2 += alb*b2f(v.z); acc3 += alb*b2f(v.w);
    }
  }
  ushort4 o;
  o.x = f2b(gelu_f(acc0 + b2l[c4+0]));
  o.y = f2b(gelu_f(acc1 + b2l[c4+1]));
  o.z = f2b(gelu_f(acc2 + b2l[c4+2]));
  o.w = f2b(gelu_f(acc3 + b2l[c4+3]));
  *(ushort4*)&hbf[d*256 + c4] = o;
}

// ---------------- pooling: contiguous chunks, register accumulate ----------------
__global__ void pool_k(const unsigned short* __restrict__ hbf, const int* __restrict__ batch,
                       float* __restrict__ pool, float* __restrict__ cnts){
  int t = threadIdx.x;
  int n0 = blockIdx.x*PBLK;
  if (n0 >= NN) return;
  int n1 = n0 + PBLK; if (n1 > NN) n1 = NN;
  float acc = 0.f;
  int cur = batch[n0], cnt = 0;
  for (int n = n0; n < n1; n++){
    int b = batch[n];
    if (b != cur){
      atomicAdd(&pool[cur*256 + t], acc);
      if (t == 0) atomicAdd(&cnts[cur], (float)cnt);
      acc = 0.f; cnt = 0; cur = b;
    }
    acc += b2f(hbf[n*256 + t]);
    cnt++;
  }
  atomicAdd(&pool[cur*256 + t], acc);
  if (t == 0) atomicAdd(&cnts[cur], (float)cnt);
}

__global__ void mlp_k(const float* __restrict__ pool, const float* __restrict__ cnts,
                      const float* __restrict__ Wl1, const float* __restrict__ bl1,
                      const float* __restrict__ Wl2, const float* __restrict__ bl2,
                      const float* __restrict__ Wl3, const float* __restrict__ bl3,
                      float* __restrict__ out){
  __shared__ float mean[256];
  __shared__ float z1[128];
  __shared__ float z2[64];
  int g = blockIdx.x, t = threadIdx.x;
  mean[t] = pool[g*256 + t] / cnts[g];
  __syncthreads();
  if (t < 128){
    float s = bl1[t];
    for (int k = 0; k < 256; k++) s += mean[k]*Wl1[k*128 + t];
    z1[t] = gelu_f(s);
  }
  __syncthreads();
  if (t < 64){
    float s = bl2[t];
    for (int k = 0; k < 128; k++) s += z1[k]*Wl2[k*64 + t];
    z2[t] = gelu_f(s);
  }
  __syncthreads();
  if (t == 0){
    float s = bl3[0];
    for (int k = 0; k < 64; k++) s += z2[k]*Wl3[k];
    out[g] = 1.f/(1.f + expf(-s));
  }
}

__global__ void eout_k(const int* __restrict__ ei, float* __restrict__ out){
  int i = blockIdx.x*256 + threadIdx.x;
  if (i >= ET) return;
  float s, d;
  if (i < EE){ s = (float)ei[i]; d = (float)ei[EE + i]; }
  else { s = (float)(i - EE); d = s; }
  out[16 + i] = s;
  out[16 + ET + i] = d;
}

extern "C" void kernel_launch(void* const* d_in, const int* in_sizes, int n_in,
                              void* d_out, int out_size, void* d_ws, size_t ws_size,
                              hipStream_t stream) {
  const float* x   = (const float*)d_in[0];
  const int*   ei  = (const int*)d_in[1];
  const int*   batch = (const int*)d_in[2];
  const float* W1  = (const float*)d_in[3];
  const float* as1 = (const float*)d_in[4];
  const float* ad1 = (const float*)d_in[5];
  const float* b1  = (const float*)d_in[6];
  const float* W2  = (const float*)d_in[7];
  const float* as2 = (const float*)d_in[8];
  const float* ad2 = (const float*)d_in[9];
  const float* b2  = (const float*)d_in[10];
  const float* Wl1 = (const float*)d_in[11];
  const float* bl1 = (const float*)d_in[12];
  const float* Wl2 = (const float*)d_in[13];
  const float* bl2 = (const float*)d_in[14];
  const float* Wl3 = (const float*)d_in[15];
  const float* bl3 = (const float*)d_in[16];
  float* out = (float*)d_out;

  unsigned short* gbf = (unsigned short*)d_ws;       // NN*DD bf16
  unsigned short* hbf = gbf + NN*DD;                 // NN*DD bf16
  unsigned short* Wt  = hbf + NN*DD;                 // 3*DD*DD bf16
  float* a_s  = (float*)(Wt + 3*DD*DD);              // NN
  float* a_d  = a_s + NN;                            // NN
  float* s4   = a_d + NN;                            // NN*NH
  float* ST   = s4  + NN*NH;                         // 8
  float* pool = ST  + 8;                             // NG*DD
  float* cnts = pool + NG*DD;                        // NG
  int* ideg   = (int*)(cnts + NG);                   // NN+1
  int* icur   = ideg + (NN + 1);                     // NN
  int* csr_s  = icur + NN;                           // ET
  int* csr_e  = csr_s + ET;                          // ET

  hipMemsetAsync(ideg, 0, sizeof(int)*(2*NN + 1), stream);
  hipMemsetAsync(pool, 0, sizeof(float)*(NG*DD + NG), stream);

  hist_k<<<(ET + 255)/256, 256, 0, stream>>>(ei, ideg);
  scan_k<<<1, 1024, 0, stream>>>(ideg);
  scatter_k<<<(ET + 255)/256, 256, 0, stream>>>(ei, ideg, icur, csr_s, csr_e);

  wtr_k<<<dim3(4,4,3), 256, 0, stream>>>(W2, Wt);
  conv1_pre_k<<<1, 256, 0, stream>>>(W1, as1, ad1, ST);
  conv1_agg_k<<<(NN*64 + 255)/256, 256, 0, stream>>>(x, ideg, csr_s, ST, s4);
  conv1_fin_k<<<NN, 256, 0, stream>>>(W1, b1, s4, hbf);

  for (int l = 0; l < 3; l++){
    hipMemsetAsync(a_s, 0, sizeof(float)*2*NN, stream);
    gemm_k<<<dim3((NN + 127)/128, 2), 256, 0, stream>>>(hbf, Wt + l*DD*DD, gbf,
                                                        as2 + l*DD, ad2 + l*DD, a_s, a_d, NN);
    aggf_k<<<(NN*64 + 255)/256, 256, 0, stream>>>(gbf, a_s, a_d, ideg, csr_s, csr_e,
                                                  b2 + l*DD, hbf,
                                                  (l == 2) ? (out + 16 + 2*ET) : (float*)nullptr);
  }

  pool_k<<<(NN + PBLK - 1)/PBLK, 256, 0, stream>>>(hbf, batch, pool, cnts);
  mlp_k<<<NG, 256, 0, stream>>>(pool, cnts, Wl1, bl1, Wl2, bl2, Wl3, bl3, out);
  eout_k<<<(ET + 255)/256, 256, 0, stream>>>(ei, out);
}

// Round 6
// 276.681 us; speedup vs baseline: 2.9858x; 1.0359x over previous
//
#include <hip/hip_runtime.h>
#include <hip/hip_bf16.h>
#include <math.h>

#define NN 20000
#define EE 320000
#define ET 340000   // EE + NN self loops
#define NG 16
#define DD 256
#define NH 4
#define PBLK 32

typedef __attribute__((ext_vector_type(8))) short bf16x8;
typedef __attribute__((ext_vector_type(4))) float f32x4;

__device__ __forceinline__ float gelu_f(float x){
  float x3 = x*x*x;
  return 0.5f*x*(1.0f + tanhf(0.7978845608028654f*(x + 0.044715f*x3)));
}
__device__ __forceinline__ float lrelu_f(float x){ return x > 0.f ? x : 0.2f*x; }
__device__ __forceinline__ unsigned short f2b(float f){
  __hip_bfloat16 b = __float2bfloat16(f);
  return *(unsigned short*)&b;
}
__device__ __forceinline__ float b2f(unsigned short u){
  __hip_bfloat16 b; *(unsigned short*)&b = u;
  return __bfloat162float(b);
}

// ---------------- zero scratch (replaces graph-captured fillBuffer) ----------------
__global__ void zero_k(int* __restrict__ p, int n){
  int i = blockIdx.x*256 + threadIdx.x;
  if (i < n) p[i] = 0;
}

// ---------------- CSR build ----------------
__global__ void hist_k(const int* __restrict__ ei, int* __restrict__ deg){
  int i = blockIdx.x*256 + threadIdx.x;
  if (i >= ET) return;
  int dst = (i < EE) ? ei[EE + i] : (i - EE);
  atomicAdd(&deg[dst], 1);
}

__global__ void scan_k(int* __restrict__ deg){
  __shared__ int wsum[16];
  __shared__ int carry;
  int t = threadIdx.x, lane = t & 63, w = t >> 6;
  if (t == 0) carry = 0;
  __syncthreads();
  for (int base = 0; base < NN; base += 1024){
    int i = base + t;
    int v = (i < NN) ? deg[i] : 0;
    int s = v;
    #pragma unroll
    for (int ofs = 1; ofs < 64; ofs <<= 1){
      int u = __shfl_up(s, ofs, 64);
      if (lane >= ofs) s += u;
    }
    if (lane == 63) wsum[w] = s;
    __syncthreads();
    if (w == 0 && lane < 16){
      int ws = wsum[lane];
      #pragma unroll
      for (int ofs = 1; ofs < 16; ofs <<= 1){
        int u = __shfl_up(ws, ofs, 64);
        if (lane >= ofs) ws += u;
      }
      wsum[lane] = ws;
    }
    __syncthreads();
    int excl = s - v + (w > 0 ? wsum[w-1] : 0) + carry;
    if (i < NN) deg[i] = excl;
    __syncthreads();
    if (t == 0) carry += wsum[15];
    __syncthreads();
  }
  if (t == 0) deg[NN] = carry;
}

__global__ void scatter_k(const int* __restrict__ ei, const int* __restrict__ off,
                          int* __restrict__ cur, int* __restrict__ cs, int* __restrict__ ce){
  int i = blockIdx.x*256 + threadIdx.x;
  if (i >= ET) return;
  int src, dst;
  if (i < EE){ src = ei[i]; dst = ei[EE + i]; } else { src = i - EE; dst = src; }
  int pos = off[dst] + atomicAdd(&cur[dst], 1);
  cs[pos] = src; ce[pos] = i;
}

// ---------------- conv1 (input dim 1 -> algebraic collapse), 1 wave/dst ----------------
__global__ void conv1_pre_k(const float* __restrict__ W1, const float* __restrict__ as1,
                            const float* __restrict__ ad1, float* __restrict__ ST){
  int t = threadIdx.x;
  float w = W1[t];
  float p = w*as1[t], q = w*ad1[t];
  for (int ofs = 32; ofs > 0; ofs >>= 1){
    p += __shfl_down(p, ofs, 64);
    q += __shfl_down(q, ofs, 64);
  }
  if ((t & 63) == 0){ ST[t>>6] = p; ST[4 + (t>>6)] = q; }
}

__global__ __launch_bounds__(256) void conv1_agg_k(const float* __restrict__ x,
                            const int* __restrict__ off,
                            const int* __restrict__ cs, const float* __restrict__ ST,
                            float* __restrict__ s4){
  int d = (blockIdx.x*256 + threadIdx.x) >> 6;
  int lane = threadIdx.x & 63;
  if (d >= NN) return;
  float S[4], T[4];
  #pragma unroll
  for (int hh = 0; hh < 4; hh++){ S[hh] = ST[hh]; T[hh] = ST[4+hh]; }
  float xd = x[d];
  int o0 = off[d], o1 = off[d+1];
  float m[4] = {-1e30f,-1e30f,-1e30f,-1e30f};
  for (int k = o0 + lane; k < o1; k += 64){
    float xs = x[cs[k]];
    #pragma unroll
    for (int hh = 0; hh < 4; hh++)
      m[hh] = fmaxf(m[hh], lrelu_f(xs*S[hh] + xd*T[hh]));
  }
  #pragma unroll
  for (int hh = 0; hh < 4; hh++)
    #pragma unroll
    for (int ofs = 32; ofs > 0; ofs >>= 1) m[hh] = fmaxf(m[hh], __shfl_xor(m[hh], ofs, 64));
  float den[4] = {0,0,0,0}, ac[4] = {0,0,0,0};
  for (int k = o0 + lane; k < o1; k += 64){
    float xs = x[cs[k]];
    #pragma unroll
    for (int hh = 0; hh < 4; hh++){
      float ex = expf(lrelu_f(xs*S[hh] + xd*T[hh]) - m[hh]);
      den[hh] += ex; ac[hh] += ex*xs;
    }
  }
  #pragma unroll
  for (int hh = 0; hh < 4; hh++){
    #pragma unroll
    for (int ofs = 32; ofs > 0; ofs >>= 1){
      den[hh] += __shfl_xor(den[hh], ofs, 64);
      ac[hh]  += __shfl_xor(ac[hh], ofs, 64);
    }
  }
  if (lane == 0){
    #pragma unroll
    for (int hh = 0; hh < 4; hh++) s4[d*4+hh] = ac[hh]/(den[hh] + 1e-16f);
  }
}

__global__ void conv1_fin_k(const float* __restrict__ W1, const float* __restrict__ b1,
                            const float* __restrict__ s4, unsigned short* __restrict__ hbf){
  int i = blockIdx.x*256 + threadIdx.x;
  int n = i >> 8; int c = i & 255;
  float v = W1[c]*s4[n*4 + (c>>6)] + b1[c];
  hbf[i] = f2b(gelu_f(v));
}

// ---------------- weight transpose to bf16: Wt[l][n][k] = W2[l][k][n] ----------------
__global__ void wtr_k(const float* __restrict__ W2, unsigned short* __restrict__ Wt){
  __shared__ float tile[64][65];
  int l = blockIdx.z;
  const float* B = W2 + l*DD*DD;
  unsigned short* O = Wt + l*DD*DD;
  int r0 = blockIdx.x*64, c0 = blockIdx.y*64;
  int t = threadIdx.x;
  int tr = t >> 4, tc4 = (t & 15)*4;
  #pragma unroll
  for (int i = 0; i < 4; i++){
    int r = tr + i*16;
    float4 v = *(const float4*)&B[(r0+r)*DD + c0 + tc4];
    tile[r][tc4+0]=v.x; tile[r][tc4+1]=v.y; tile[r][tc4+2]=v.z; tile[r][tc4+3]=v.w;
  }
  __syncthreads();
  #pragma unroll
  for (int i = 0; i < 4; i++){
    int c = tr + i*16;
    ushort4 o;
    o.x = f2b(tile[tc4+0][c]);
    o.y = f2b(tile[tc4+1][c]);
    o.z = f2b(tile[tc4+2][c]);
    o.w = f2b(tile[tc4+3][c]);
    *(ushort4*)&O[(c0+c)*DD + r0 + tc4] = o;
  }
}

// -------- bf16 MFMA GEMM + fused partial a_s/a_d dots (non-atomic) --------
__global__ __launch_bounds__(256) void gemm_k(const unsigned short* __restrict__ A,
                                              const unsigned short* __restrict__ Bt,
                                              unsigned short* __restrict__ Cb,
                                              const float* __restrict__ asv,
                                              const float* __restrict__ adv,
                                              float* __restrict__ asp,
                                              float* __restrict__ adp, int M){
  __shared__ unsigned short As[128][48];
  __shared__ unsigned short Bs[128][48];
  int tid = threadIdx.x;
  int lane = tid & 63, w = tid >> 6;
  int wm = w >> 1, wn = w & 1;
  int bm = blockIdx.x*128, bn = blockIdx.y*128;
  f32x4 acc[4][4] = {};
  int r = tid >> 2, cb = (tid & 3) * 8;
  for (int k0 = 0; k0 < 256; k0 += 32){
    #pragma unroll
    for (int hh = 0; hh < 2; hh++){
      int row = bm + r + hh*64;
      bf16x8 v = {};
      if (row < M) v = *(const bf16x8*)&A[row*256 + k0 + cb];
      *(bf16x8*)&As[r + hh*64][cb] = v;
      *(bf16x8*)&Bs[r + hh*64][cb] = *(const bf16x8*)&Bt[(bn + r + hh*64)*256 + k0 + cb];
    }
    __syncthreads();
    bf16x8 af[4], bfr[4];
    int kk = (lane >> 4) * 8;
    int rl = lane & 15;
    #pragma unroll
    for (int i = 0; i < 4; i++) af[i] = *(const bf16x8*)&As[wm*64 + i*16 + rl][kk];
    #pragma unroll
    for (int j = 0; j < 4; j++) bfr[j] = *(const bf16x8*)&Bs[wn*64 + j*16 + rl][kk];
    #pragma unroll
    for (int i = 0; i < 4; i++)
      #pragma unroll
      for (int j = 0; j < 4; j++)
        acc[i][j] = __builtin_amdgcn_mfma_f32_16x16x32_bf16(af[i], bfr[j], acc[i][j], 0,0,0);
    __syncthreads();
  }
  int cl = lane & 15, rg = (lane >> 4) * 4;
  float asl[4], adl[4];
  #pragma unroll
  for (int j = 0; j < 4; j++){
    int col = bn + wn*64 + j*16 + cl;
    asl[j] = asv[col]; adl[j] = adv[col];
  }
  int part = blockIdx.y*NN;
  #pragma unroll
  for (int i = 0; i < 4; i++){
    #pragma unroll
    for (int rr = 0; rr < 4; rr++){
      int row = bm + wm*64 + i*16 + rg + rr;
      if (row < M){
        float p = 0.f, q = 0.f;
        #pragma unroll
        for (int j = 0; j < 4; j++){
          float v = acc[i][j][rr];
          p += v*asl[j]; q += v*adl[j];
          Cb[row*256 + bn + wn*64 + j*16 + cl] = f2b(v);
        }
        #pragma unroll
        for (int ofs = 1; ofs < 16; ofs <<= 1){
          p += __shfl_xor(p, ofs, 64);
          q += __shfl_xor(q, ofs, 64);
        }
        if (cl == 0){
          asp[part + row] = p;
          adp[part + row] = q;
        }
      }
    }
  }
}

// ---------------- sum the 2 column-block partials ----------------
__global__ void asum_k(const float* __restrict__ asp, const float* __restrict__ adp,
                       float* __restrict__ a_s, float* __restrict__ a_d){
  int i = blockIdx.x*256 + threadIdx.x;
  if (i >= NN) return;
  a_s[i] = asp[i] + asp[NN + i];
  a_d[i] = adp[i] + adp[NN + i];
}

// ------- fused softmax + weighted gather-sum (1 wave / dst node) -------
__global__ __launch_bounds__(256) void aggf_k(const unsigned short* __restrict__ gbf,
    const float* __restrict__ a_s, const float* __restrict__ a_d,
    const int* __restrict__ off, const int* __restrict__ cs, const int* __restrict__ ce,
    const float* __restrict__ b2l, unsigned short* __restrict__ hbf,
    float* __restrict__ alpha_out){
  int d = (blockIdx.x*256 + threadIdx.x) >> 6;
  int lane = threadIdx.x & 63;
  if (d >= NN) return;
  int o0 = off[d], o1 = off[d+1];
  float add = a_d[d];
  // pass 1: max
  float m = -1e30f;
  for (int k = o0 + lane; k < o1; k += 64)
    m = fmaxf(m, lrelu_f(a_s[cs[k]] + add));
  #pragma unroll
  for (int ofs = 32; ofs > 0; ofs >>= 1) m = fmaxf(m, __shfl_xor(m, ofs, 64));
  // pass 2: denom
  float den = 0.f;
  for (int k = o0 + lane; k < o1; k += 64)
    den += expf(lrelu_f(a_s[cs[k]] + add) - m);
  #pragma unroll
  for (int ofs = 32; ofs > 0; ofs >>= 1) den += __shfl_xor(den, ofs, 64);
  float inv = 1.0f/(den + 1e-16f);
  // pass 3: chunked broadcast + 8x-unrolled gather
  int c4 = lane*4;
  const unsigned short* gp = gbf + c4;
  float acc0=0.f, acc1=0.f, acc2=0.f, acc3=0.f;
  for (int base = o0; base < o1; base += 64){
    int k = base + lane;
    float al = 0.f; int s = 0;
    if (k < o1){
      s = cs[k];
      al = expf(lrelu_f(a_s[s] + add) - m)*inv;
      if (alpha_out) alpha_out[ce[k]] = al;
    }
    int cnt = min(64, o1 - base);
    int kk = 0;
    for (; kk + 8 <= cnt; kk += 8){
      float alv[8]; int sv[8];
      #pragma unroll
      for (int u = 0; u < 8; u++){
        alv[u] = __shfl(al, kk+u, 64);
        sv[u]  = __shfl(s,  kk+u, 64);
      }
      ushort4 v[8];
      #pragma unroll
      for (int u = 0; u < 8; u++) v[u] = *(const ushort4*)&gp[sv[u]*256];
      #pragma unroll
      for (int u = 0; u < 8; u++){
        acc0 += alv[u]*b2f(v[u].x);
        acc1 += alv[u]*b2f(v[u].y);
        acc2 += alv[u]*b2f(v[u].z);
        acc3 += alv[u]*b2f(v[u].w);
      }
    }
    for (; kk < cnt; kk++){
      float alb = __shfl(al, kk, 64);
      int   sb  = __shfl(s, kk, 64);
      ushort4 v = *(const ushort4*)&gp[sb*256];
      acc0 += alb*b2f(v.x); acc1 += alb*b2f(v.y);
      acc2 += alb*b2f(v.z); acc3 += alb*b2f(v.w);
    }
  }
  ushort4 o;
  o.x = f2b(gelu_f(acc0 + b2l[c4+0]));
  o.y = f2b(gelu_f(acc1 + b2l[c4+1]));
  o.z = f2b(gelu_f(acc2 + b2l[c4+2]));
  o.w = f2b(gelu_f(acc3 + b2l[c4+3]));
  *(ushort4*)&hbf[d*256 + c4] = o;
}

// ---------------- pooling: contiguous chunks, register accumulate ----------------
__global__ void pool_k(const unsigned short* __restrict__ hbf, const int* __restrict__ batch,
                       float* __restrict__ pool, float* __restrict__ cnts){
  int t = threadIdx.x;
  int n0 = blockIdx.x*PBLK;
  if (n0 >= NN) return;
  int n1 = n0 + PBLK; if (n1 > NN) n1 = NN;
  float acc = 0.f;
  int cur = batch[n0], cnt = 0;
  for (int n = n0; n < n1; n++){
    int b = batch[n];
    if (b != cur){
      atomicAdd(&pool[cur*256 + t], acc);
      if (t == 0) atomicAdd(&cnts[cur], (float)cnt);
      acc = 0.f; cnt = 0; cur = b;
    }
    acc += b2f(hbf[n*256 + t]);
    cnt++;
  }
  atomicAdd(&pool[cur*256 + t], acc);
  if (t == 0) atomicAdd(&cnts[cur], (float)cnt);
}

__global__ void mlp_k(const float* __restrict__ pool, const float* __restrict__ cnts,
                      const float* __restrict__ Wl1, const float* __restrict__ bl1,
                      const float* __restrict__ Wl2, const float* __restrict__ bl2,
                      const float* __restrict__ Wl3, const float* __restrict__ bl3,
                      float* __restrict__ out){
  __shared__ float mean[256];
  __shared__ float z1[128];
  __shared__ float z2[64];
  int g = blockIdx.x, t = threadIdx.x;
  mean[t] = pool[g*256 + t] / cnts[g];
  __syncthreads();
  if (t < 128){
    float s = bl1[t];
    for (int k = 0; k < 256; k++) s += mean[k]*Wl1[k*128 + t];
    z1[t] = gelu_f(s);
  }
  __syncthreads();
  if (t < 64){
    float s = bl2[t];
    for (int k = 0; k < 128; k++) s += z1[k]*Wl2[k*64 + t];
    z2[t] = gelu_f(s);
  }
  __syncthreads();
  if (t == 0){
    float s = bl3[0];
    for (int k = 0; k < 64; k++) s += z2[k]*Wl3[k];
    out[g] = 1.f/(1.f + expf(-s));
  }
}

__global__ void eout_k(const int* __restrict__ ei, float* __restrict__ out){
  int i = blockIdx.x*256 + threadIdx.x;
  if (i >= ET) return;
  float s, d;
  if (i < EE){ s = (float)ei[i]; d = (float)ei[EE + i]; }
  else { s = (float)(i - EE); d = s; }
  out[16 + i] = s;
  out[16 + ET + i] = d;
}

extern "C" void kernel_launch(void* const* d_in, const int* in_sizes, int n_in,
                              void* d_out, int out_size, void* d_ws, size_t ws_size,
                              hipStream_t stream) {
  const float* x   = (const float*)d_in[0];
  const int*   ei  = (const int*)d_in[1];
  const int*   batch = (const int*)d_in[2];
  const float* W1  = (const float*)d_in[3];
  const float* as1 = (const float*)d_in[4];
  const float* ad1 = (const float*)d_in[5];
  const float* b1  = (const float*)d_in[6];
  const float* W2  = (const float*)d_in[7];
  const float* as2 = (const float*)d_in[8];
  const float* ad2 = (const float*)d_in[9];
  const float* b2  = (const float*)d_in[10];
  const float* Wl1 = (const float*)d_in[11];
  const float* bl1 = (const float*)d_in[12];
  const float* Wl2 = (const float*)d_in[13];
  const float* bl2 = (const float*)d_in[14];
  const float* Wl3 = (const float*)d_in[15];
  const float* bl3 = (const float*)d_in[16];
  float* out = (float*)d_out;

  unsigned short* gbf = (unsigned short*)d_ws;       // NN*DD bf16
  unsigned short* hbf = gbf + NN*DD;                 // NN*DD bf16
  unsigned short* Wt  = hbf + NN*DD;                 // 3*DD*DD bf16
  float* asp  = (float*)(Wt + 3*DD*DD);              // 2*NN
  float* adp  = asp + 2*NN;                          // 2*NN
  float* a_s  = adp + 2*NN;                          // NN
  float* a_d  = a_s + NN;                            // NN
  float* s4   = a_d + NN;                            // NN*NH
  float* ST   = s4  + NN*NH;                         // 8
  float* pool = ST  + 8;                             // NG*DD   --+ contiguous
  float* cnts = pool + NG*DD;                        // NG        | zero
  int* ideg   = (int*)(cnts + NG);                   // NN+1      | region
  int* icur   = ideg + (NN + 1);                     // NN      --+
  int* csr_s  = icur + NN;                           // ET
  int* csr_e  = csr_s + ET;                          // ET

  const int zn = NG*DD + NG + (NN + 1) + NN;         // 44113 words
  zero_k<<<(zn + 255)/256, 256, 0, stream>>>((int*)pool, zn);

  hist_k<<<(ET + 255)/256, 256, 0, stream>>>(ei, ideg);
  scan_k<<<1, 1024, 0, stream>>>(ideg);
  scatter_k<<<(ET + 255)/256, 256, 0, stream>>>(ei, ideg, icur, csr_s, csr_e);

  wtr_k<<<dim3(4,4,3), 256, 0, stream>>>(W2, Wt);
  conv1_pre_k<<<1, 256, 0, stream>>>(W1, as1, ad1, ST);
  conv1_agg_k<<<(NN*64 + 255)/256, 256, 0, stream>>>(x, ideg, csr_s, ST, s4);
  conv1_fin_k<<<NN, 256, 0, stream>>>(W1, b1, s4, hbf);

  for (int l = 0; l < 3; l++){
    gemm_k<<<dim3((NN + 127)/128, 2), 256, 0, stream>>>(hbf, Wt + l*DD*DD, gbf,
                                                        as2 + l*DD, ad2 + l*DD, asp, adp, NN);
    asum_k<<<(NN + 255)/256, 256, 0, stream>>>(asp, adp, a_s, a_d);
    aggf_k<<<(NN*64 + 255)/256, 256, 0, stream>>>(gbf, a_s, a_d, ideg, csr_s, csr_e,
                                                  b2 + l*DD, hbf,
                                                  (l == 2) ? (out + 16 + 2*ET) : (float*)nullptr);
  }

  pool_k<<<(NN + PBLK - 1)/PBLK, 256, 0, stream>>>(hbf, batch, pool, cnts);
  mlp_k<<<NG, 256, 0, stream>>>(pool, cnts, Wl1, bl1, Wl2, bl2, Wl3, bl3, out);
  eout_k<<<(ET + 255)/256, 256, 0, stream>>>(ei, out);
}